// Round 2
// baseline (786.492 us; speedup 1.0000x reference)
//
#include <hip/hip_runtime.h>
#include <math.h>

#define N_NODES 50000
#define N_EDGES 800000
#define E2 (N_EDGES + N_NODES)   // with self loops
#define F_IN 512
#define HEADS 8
#define HID 32
#define HC 256                    // HEADS*HID
#define NCLASS 32
#define NEG_SLOPE 0.2f

// ---------------------------------------------------------------- CSR build
__global__ void count_deg(const int* __restrict__ ei, int* __restrict__ deg) {
    int e = blockIdx.x * blockDim.x + threadIdx.x;
    if (e >= E2) return;
    int dst = (e < N_EDGES) ? ei[N_EDGES + e] : (e - N_EDGES);
    atomicAdd(&deg[dst], 1);
}

#define SCAN_B 256
#define SCAN_NB ((N_NODES + SCAN_B - 1) / SCAN_B)   // 196

__global__ void scan1_kernel(const int* __restrict__ deg, int* __restrict__ rowstart,
                             int* __restrict__ blocksum) {
    __shared__ int sm[SCAN_B];
    int t = threadIdx.x, i = blockIdx.x * SCAN_B + t;
    int v = (i < N_NODES) ? deg[i] : 0;
    sm[t] = v; __syncthreads();
    int x = v;
    for (int off = 1; off < SCAN_B; off <<= 1) {
        int y = (t >= off) ? sm[t - off] : 0; __syncthreads();
        x += y; sm[t] = x; __syncthreads();
    }
    if (i < N_NODES) rowstart[i] = x - v;            // block-local exclusive
    if (t == SCAN_B - 1) blocksum[blockIdx.x] = x;   // block total
}

__global__ void scan2_kernel(const int* __restrict__ blocksum, int* __restrict__ blockoff,
                             int* __restrict__ rowstart) {
    __shared__ int sm[256];
    int t = threadIdx.x;
    int v = (t < SCAN_NB) ? blocksum[t] : 0;
    sm[t] = v; __syncthreads();
    int x = v;
    for (int off = 1; off < 256; off <<= 1) {
        int y = (t >= off) ? sm[t - off] : 0; __syncthreads();
        x += y; sm[t] = x; __syncthreads();
    }
    if (t < SCAN_NB) blockoff[t] = x - v;            // exclusive block offsets
    if (t == 255) rowstart[N_NODES] = x;             // grand total
}

__global__ void scan3_kernel(int* __restrict__ rowstart, const int* __restrict__ blockoff) {
    int i = blockIdx.x * 256 + threadIdx.x;
    if (i < N_NODES) rowstart[i] += blockoff[i >> 8];
}

__global__ void fill_csr(const int* __restrict__ ei, const int* __restrict__ rowstart,
                         int* __restrict__ cursor, int* __restrict__ csr_src) {
    int e = blockIdx.x * blockDim.x + threadIdx.x;
    if (e >= E2) return;
    int src, dst;
    if (e < N_EDGES) { src = ei[e]; dst = ei[N_EDGES + e]; }
    else             { src = e - N_EDGES; dst = src; }
    int p = atomicAdd(&cursor[dst], 1);
    csr_src[rowstart[dst] + p] = src;
}

// ---------------------------------------------------------------- fp32 GEMM 128x128 (layer 1)
// C[M,NOUT] = A[M,K] @ B[K,NOUT]; 256 threads; TM=TN=8; BK=16
template<int K, int NOUT>
__global__ void __launch_bounds__(256) gemm128_kernel(const float* __restrict__ A,
                                                      const float* __restrict__ B,
                                                      float* __restrict__ C, int M) {
    constexpr int BM = 128, BN = 128, BK = 16;
    __shared__ float As[BK][BM];
    __shared__ float Bs[BK][BN];
    const int tid = threadIdx.x;
    const int bm = blockIdx.x * BM;
    const int bn = blockIdx.y * BN;
    const int tx = tid & 15;     // 16 threads along N, each owns cols tx*4..+3 and 64+tx*4..+3
    const int ty = tid >> 4;     // 16 threads along M, each owns rows ty*8..+7
    float acc[8][8] = {};

    for (int k0 = 0; k0 < K; k0 += BK) {
        #pragma unroll
        for (int p = 0; p < 2; ++p) {
            int i = tid + p * 256;
            // A tile: 128 rows x 16 k = 512 float4 (4 per row)
            int row = i >> 2, kc = (i & 3) << 2;
            float4 v = make_float4(0.f, 0.f, 0.f, 0.f);
            int gr = bm + row;
            if (gr < M) v = *(const float4*)(A + (size_t)gr * K + k0 + kc);
            As[kc + 0][row] = v.x; As[kc + 1][row] = v.y;
            As[kc + 2][row] = v.z; As[kc + 3][row] = v.w;
            // B tile: 16 rows x 128 cols = 512 float4
            int brow = i >> 5, bnc = (i & 31) << 2;
            float4 w = *(const float4*)(B + (size_t)(k0 + brow) * NOUT + bn + bnc);
            *(float4*)&Bs[brow][bnc] = w;
        }
        __syncthreads();
        #pragma unroll
        for (int k = 0; k < BK; ++k) {
            float4 a0 = *(float4*)&As[k][ty * 8];
            float4 a1 = *(float4*)&As[k][ty * 8 + 4];
            float4 b0 = *(float4*)&Bs[k][tx * 4];
            float4 b1 = *(float4*)&Bs[k][64 + tx * 4];
            float af[8] = {a0.x, a0.y, a0.z, a0.w, a1.x, a1.y, a1.z, a1.w};
            float bf[8] = {b0.x, b0.y, b0.z, b0.w, b1.x, b1.y, b1.z, b1.w};
            #pragma unroll
            for (int i = 0; i < 8; ++i)
                #pragma unroll
                for (int j = 0; j < 8; ++j)
                    acc[i][j] += af[i] * bf[j];
        }
        __syncthreads();
    }
    #pragma unroll
    for (int i = 0; i < 8; ++i) {
        int gr = bm + ty * 8 + i;
        if (gr >= M) continue;
        float* cp = C + (size_t)gr * NOUT + bn;
        *(float4*)(cp + tx * 4)      = make_float4(acc[i][0], acc[i][1], acc[i][2], acc[i][3]);
        *(float4*)(cp + 64 + tx * 4) = make_float4(acc[i][4], acc[i][5], acc[i][6], acc[i][7]);
    }
}

// ---------------------------------------------------------------- fp32 GEMM small-N (layer 2)
template<int BM, int BN, int BK, int TM, int TN, int K, int NOUT>
__global__ void __launch_bounds__(256) gemm_kernel(const float* __restrict__ A,
                                                   const float* __restrict__ B,
                                                   float* __restrict__ C, int M) {
    __shared__ float As[BK][BM];
    __shared__ float Bs[BK][BN];
    const int tid = threadIdx.x;
    const int bm = blockIdx.x * BM;
    const int bn = blockIdx.y * BN;
    constexpr int TX = BN / TN;
    const int tx = tid % TX;
    const int ty = tid / TX;
    float acc[TM][TN] = {};
    constexpr int A4 = BM * BK / 4;
    constexpr int AR = BK / 4;
    constexpr int B4 = BK * BN / 4;
    constexpr int BR = BN / 4;

    for (int k0 = 0; k0 < K; k0 += BK) {
        for (int i = tid; i < A4; i += 256) {
            int row = i / AR;
            int kc  = (i % AR) * 4;
            float4 v = make_float4(0.f, 0.f, 0.f, 0.f);
            int grow = bm + row;
            if (grow < M) v = *(const float4*)(A + (size_t)grow * K + k0 + kc);
            As[kc + 0][row] = v.x; As[kc + 1][row] = v.y;
            As[kc + 2][row] = v.z; As[kc + 3][row] = v.w;
        }
        for (int i = tid; i < B4; i += 256) {
            int row = i / BR;
            int nc  = (i % BR) * 4;
            *(float4*)&Bs[row][nc] = *(const float4*)(B + (size_t)(k0 + row) * NOUT + bn + nc);
        }
        __syncthreads();
        #pragma unroll
        for (int k = 0; k < BK; ++k) {
            float af[TM], bf[TN];
            #pragma unroll
            for (int i = 0; i < TM; ++i) af[i] = As[k][ty * TM + i];
            #pragma unroll
            for (int j = 0; j < TN; ++j) bf[j] = Bs[k][tx * TN + j];
            #pragma unroll
            for (int i = 0; i < TM; ++i)
                #pragma unroll
                for (int j = 0; j < TN; ++j)
                    acc[i][j] += af[i] * bf[j];
        }
        __syncthreads();
    }
    #pragma unroll
    for (int i = 0; i < TM; ++i) {
        int grow = bm + ty * TM + i;
        if (grow >= M) continue;
        float* cp = C + (size_t)grow * NOUT + bn + tx * TN;
        if (TN == 4)      *(float4*)cp = make_float4(acc[i][0], acc[i][1], acc[i][2], acc[i][3]);
        else if (TN == 2) *(float2*)cp = make_float2(acc[i][0], acc[i][1]);
        else for (int j = 0; j < TN; ++j) cp[j] = acc[i][j];
    }
}

// ---------------------------------------------------------------- scores
__global__ void scores1_kernel(const float* __restrict__ h, const float* __restrict__ asrc,
                               const float* __restrict__ adst,
                               float* __restrict__ ssrc, float* __restrict__ sdst) {
    int gid = blockIdx.x * blockDim.x + threadIdx.x;
    int n = gid >> 3, hh = gid & 7;
    if (n >= N_NODES) return;
    const float* hp = h + (size_t)n * HC + hh * HID;
    const float* as = asrc + hh * HID;
    const float* ad = adst + hh * HID;
    float s1 = 0.f, s2 = 0.f;
    #pragma unroll
    for (int c = 0; c < HID; ++c) { float v = hp[c]; s1 += v * as[c]; s2 += v * ad[c]; }
    ssrc[n * HEADS + hh] = s1;
    sdst[n * HEADS + hh] = s2;
}

__global__ void scores2_kernel(const float* __restrict__ h2, const float* __restrict__ asrc,
                               const float* __restrict__ adst,
                               float* __restrict__ ssrc, float* __restrict__ sdst) {
    int n = blockIdx.x * blockDim.x + threadIdx.x;
    if (n >= N_NODES) return;
    float s1 = 0.f, s2 = 0.f;
    #pragma unroll
    for (int c = 0; c < NCLASS; ++c) {
        float v = h2[(size_t)n * NCLASS + c];
        s1 += v * asrc[c]; s2 += v * adst[c];
    }
    ssrc[n] = s1; sdst[n] = s2;
}

// ---------------------------------------------------------------- layer-1 aggregation
// one wave (64 lanes) per node, wave-synchronous. lane -> head group hg=lane>>3,
// channel quad c4 = lane*4 (head of those channels == hg).
__global__ void __launch_bounds__(256) agg1_wave_kernel(const float* __restrict__ h,
        const float* __restrict__ ssrc, const float* __restrict__ sdst,
        const int* __restrict__ rowstart, const int* __restrict__ csr_src,
        const float* __restrict__ bias, float* __restrict__ out) {
    const int wid = (blockIdx.x * blockDim.x + threadIdx.x) >> 6;   // node id
    if (wid >= N_NODES) return;
    const int lane = threadIdx.x & 63;
    const int hg = lane >> 3;       // head this lane serves
    const int hl = lane & 7;        // lane-in-head for phase 1
    const int n = wid;
    const int beg = rowstart[n], end = rowstart[n + 1];
    const float sdst_n = sdst[(size_t)n * HEADS + hg];

    // phase 1: per-head online softmax over edges, 8 lanes per head
    float m = -INFINITY, s = 0.f;
    for (int e = beg + hl; e < end; e += 8) {
        int src = csr_src[e];
        float sc = ssrc[(size_t)src * HEADS + hg] + sdst_n;
        sc = sc > 0.f ? sc : NEG_SLOPE * sc;
        float nm = fmaxf(m, sc);
        s = s * __expf(m - nm) + __expf(sc - nm);
        m = nm;
    }
    #pragma unroll
    for (int off = 4; off > 0; off >>= 1) {
        float om = __shfl_xor(m, off);
        float os = __shfl_xor(s, off);
        float nm = fmaxf(m, om);
        float a = (m  == -INFINITY) ? 0.f : s  * __expf(m  - nm);
        float b = (om == -INFINITY) ? 0.f : os * __expf(om - nm);
        m = nm; s = a + b;
    }
    // all 8 lanes of each head group now hold that head's (m, s)

    // phase 2: acc over edges, float4 of channels per lane, 2 edges in flight
    float4 acc = make_float4(0.f, 0.f, 0.f, 0.f);
    const float* hc = h + (size_t)lane * 4;
    int e = beg;
    for (; e + 1 < end; e += 2) {
        int s0 = csr_src[e], s1 = csr_src[e + 1];
        float x0 = ssrc[(size_t)s0 * HEADS + hg] + sdst_n;
        float x1 = ssrc[(size_t)s1 * HEADS + hg] + sdst_n;
        float4 h0 = *(const float4*)(hc + (size_t)s0 * HC);
        float4 h1 = *(const float4*)(hc + (size_t)s1 * HC);
        x0 = x0 > 0.f ? x0 : NEG_SLOPE * x0;
        x1 = x1 > 0.f ? x1 : NEG_SLOPE * x1;
        float w0 = __expf(x0 - m), w1 = __expf(x1 - m);
        acc.x += w0 * h0.x + w1 * h1.x;
        acc.y += w0 * h0.y + w1 * h1.y;
        acc.z += w0 * h0.z + w1 * h1.z;
        acc.w += w0 * h0.w + w1 * h1.w;
    }
    if (e < end) {
        int s0 = csr_src[e];
        float x0 = ssrc[(size_t)s0 * HEADS + hg] + sdst_n;
        x0 = x0 > 0.f ? x0 : NEG_SLOPE * x0;
        float w0 = __expf(x0 - m);
        float4 h0 = *(const float4*)(hc + (size_t)s0 * HC);
        acc.x += w0 * h0.x; acc.y += w0 * h0.y;
        acc.z += w0 * h0.z; acc.w += w0 * h0.w;
    }
    float inv = 1.f / (s + 1e-16f);
    float4 bv = *(const float4*)(bias + lane * 4);
    float4 o;
    o.x = acc.x * inv + bv.x; o.y = acc.y * inv + bv.y;
    o.z = acc.z * inv + bv.z; o.w = acc.w * inv + bv.w;
    // ELU
    o.x = o.x > 0.f ? o.x : expm1f(o.x);
    o.y = o.y > 0.f ? o.y : expm1f(o.y);
    o.z = o.z > 0.f ? o.z : expm1f(o.z);
    o.w = o.w > 0.f ? o.w : expm1f(o.w);
    *(float4*)(out + (size_t)n * HC + lane * 4) = o;
}

// ---------------------------------------------------------------- layer-2 aggregation
// one wave (64 threads) per node; H=1, C=32
__global__ void __launch_bounds__(64) agg2_kernel(const float* __restrict__ h2,
        const float* __restrict__ ssrc, const float* __restrict__ sdst,
        const int* __restrict__ rowstart, const int* __restrict__ csr_src,
        const float* __restrict__ bias, float* __restrict__ out) {
    const int n = blockIdx.x;
    const int beg = rowstart[n], end = rowstart[n + 1];
    const int t = threadIdx.x;
    const float sdst_n = sdst[n];

    float m = -INFINITY, s = 0.f;
    for (int e = beg + t; e < end; e += 64) {
        float sc = ssrc[csr_src[e]] + sdst_n;
        sc = sc > 0.f ? sc : NEG_SLOPE * sc;
        float nm = fmaxf(m, sc);
        s = s * __expf(m - nm) + __expf(sc - nm);
        m = nm;
    }
    #pragma unroll
    for (int off = 32; off > 0; off >>= 1) {
        float om = __shfl_xor(m, off);
        float os = __shfl_xor(s, off);
        float nm = fmaxf(m, om);
        float a = (m  == -INFINITY) ? 0.f : s  * __expf(m  - nm);
        float b = (om == -INFINITY) ? 0.f : os * __expf(om - nm);
        m = nm; s = a + b;
    }
    const int c = t & 31, half = t >> 5;
    float acc = 0.f;
    for (int e = beg + half; e < end; e += 2) {
        int src = csr_src[e];
        float sc = ssrc[src] + sdst_n;
        sc = sc > 0.f ? sc : NEG_SLOPE * sc;
        acc += __expf(sc - m) * h2[(size_t)src * NCLASS + c];
    }
    acc += __shfl_down(acc, 32);
    if (t < 32) out[(size_t)n * NCLASS + c] = acc / (s + 1e-16f) + bias[c] + 1e-6f;
}

// ---------------------------------------------------------------- launcher
extern "C" void kernel_launch(void* const* d_in, const int* in_sizes, int n_in,
                              void* d_out, int out_size, void* d_ws, size_t ws_size,
                              hipStream_t stream) {
    const float* x        = (const float*)d_in[0];
    const int*   ei       = (const int*)  d_in[1];
    const float* W1       = (const float*)d_in[2];
    const float* att_src1 = (const float*)d_in[3];
    const float* att_dst1 = (const float*)d_in[4];
    const float* b1       = (const float*)d_in[5];
    const float* W2       = (const float*)d_in[6];
    const float* att_src2 = (const float*)d_in[7];
    const float* att_dst2 = (const float*)d_in[8];
    const float* b2       = (const float*)d_in[9];
    float* out = (float*)d_out;

    // workspace layout
    float* ws    = (float*)d_ws;
    float* h1    = ws;                                 // N*HC
    float* out1  = h1 + (size_t)N_NODES * HC;          // N*HC
    float* h2    = out1 + (size_t)N_NODES * HC;        // N*NCLASS
    float* ssrc1 = h2 + (size_t)N_NODES * NCLASS;      // N*HEADS
    float* sdst1 = ssrc1 + (size_t)N_NODES * HEADS;    // N*HEADS
    float* ssrc2 = sdst1 + (size_t)N_NODES * HEADS;    // N
    float* sdst2 = ssrc2 + N_NODES;                    // N
    int* rowstart = (int*)(sdst2 + N_NODES);           // N+1
    int* deg      = rowstart + N_NODES + 1;            // N
    int* cursor   = deg + N_NODES;                     // N
    int* csr_src  = cursor + N_NODES;                  // E2
    int* blocksum = csr_src + E2;                      // SCAN_NB
    int* blockoff = blocksum + SCAN_NB;                // SCAN_NB

    // CSR build (ws is re-poisoned every call)
    hipMemsetAsync(deg, 0, N_NODES * sizeof(int), stream);
    hipMemsetAsync(cursor, 0, N_NODES * sizeof(int), stream);
    int eb = (E2 + 255) / 256;
    count_deg<<<eb, 256, 0, stream>>>(ei, deg);
    scan1_kernel<<<SCAN_NB, SCAN_B, 0, stream>>>(deg, rowstart, blocksum);
    scan2_kernel<<<1, 256, 0, stream>>>(blocksum, blockoff, rowstart);
    scan3_kernel<<<SCAN_NB, SCAN_B, 0, stream>>>(rowstart, blockoff);
    fill_csr<<<eb, 256, 0, stream>>>(ei, rowstart, cursor, csr_src);

    // layer 1
    {
        dim3 grid((N_NODES + 127) / 128, HC / 128);
        gemm128_kernel<F_IN, HC><<<grid, 256, 0, stream>>>(x, W1, h1, N_NODES);
    }
    scores1_kernel<<<(N_NODES * HEADS + 255) / 256, 256, 0, stream>>>(h1, att_src1, att_dst1, ssrc1, sdst1);
    agg1_wave_kernel<<<(N_NODES + 3) / 4, 256, 0, stream>>>(h1, ssrc1, sdst1, rowstart, csr_src, b1, out1);

    // layer 2
    {
        dim3 grid((N_NODES + 63) / 64, NCLASS / 32);
        gemm_kernel<64, 32, 16, 4, 2, HC, NCLASS><<<grid, 256, 0, stream>>>(out1, W2, h2, N_NODES);
    }
    scores2_kernel<<<(N_NODES + 255) / 256, 256, 0, stream>>>(h2, att_src2, att_dst2, ssrc2, sdst2);
    agg2_kernel<<<N_NODES, 64, 0, stream>>>(h2, ssrc2, sdst2, rowstart, csr_src, b2, out);
}

// Round 3
// 561.263 us; speedup vs baseline: 1.4013x; 1.4013x over previous
//
#include <hip/hip_runtime.h>
#include <math.h>

#define N_NODES 50000
#define N_EDGES 800000
#define E2 (N_EDGES + N_NODES)   // with self loops
#define F_IN 512
#define HEADS 8
#define HID 32
#define HC 256                    // HEADS*HID
#define NCLASS 32
#define NEG_SLOPE 0.2f

typedef unsigned int uint;
typedef unsigned short ushort;
typedef __attribute__((ext_vector_type(8))) short bf16x8;   // 8 bf16 (4 VGPRs)
typedef __attribute__((ext_vector_type(4))) float f32x4;

#define GLOBAL_LOAD_LDS16(g, l) \
    __builtin_amdgcn_global_load_lds((const __attribute__((address_space(1))) void*)(g), \
                                     (__attribute__((address_space(3))) void*)(l), 16, 0, 0)

__device__ inline uint bf16_rne_bits(float f) {
    uint u = __float_as_uint(f);
    return (u + 0x7fffu + ((u >> 16) & 1u)) >> 16;
}

// ------------------------------------------------ split x in place: fp32 -> (hi<<16)|lo
__global__ void split_x_kernel(float* __restrict__ x) {
    size_t i = ((size_t)blockIdx.x * blockDim.x + threadIdx.x) * 4;  // 25.6M elems, /4 exact
    float4 v = *(float4*)(x + i);
    uint4 p;
    {
        uint h = bf16_rne_bits(v.x); float r = v.x - __uint_as_float(h << 16);
        p.x = (h << 16) | bf16_rne_bits(r);
    }
    {
        uint h = bf16_rne_bits(v.y); float r = v.y - __uint_as_float(h << 16);
        p.y = (h << 16) | bf16_rne_bits(r);
    }
    {
        uint h = bf16_rne_bits(v.z); float r = v.z - __uint_as_float(h << 16);
        p.z = (h << 16) | bf16_rne_bits(r);
    }
    {
        uint h = bf16_rne_bits(v.w); float r = v.w - __uint_as_float(h << 16);
        p.w = (h << 16) | bf16_rne_bits(r);
    }
    *(uint4*)(x + i) = p;
}

// ------------------------------------------------ W1 [512][256] -> W1^T hi/lo bf16 [256][512]
__global__ void split_w1t_kernel(const float* __restrict__ W1,
                                 ushort* __restrict__ hi, ushort* __restrict__ lo) {
    int t = blockIdx.x * 256 + threadIdx.x;      // t = n*512 + k, t < 131072
    int n = t >> 9, k = t & 511;
    float f = W1[k * 256 + n];
    uint h = bf16_rne_bits(f);
    float r = f - __uint_as_float(h << 16);
    hi[t] = (ushort)h;
    lo[t] = (ushort)bf16_rne_bits(r);
}

// ------------------------------------------------ MFMA GEMM1: C[M,256] = x @ W1 (split bf16, 3-term)
// xp: [M][512] packed hi|lo u32; bhi/blo: [256][512] bf16 (W1^T)
__global__ void __launch_bounds__(256) gemm1_mfma_kernel(const uint* __restrict__ xp,
        const ushort* __restrict__ bhi, const ushort* __restrict__ blo,
        float* __restrict__ C, int M) {
    __shared__ uint   As[128 * 32];   // 16 KB packed, chunk-swizzled: phys chunk = row*8 + (c ^ (row&7))
    __shared__ ushort Bh[128 * 32];   // 8 KB,  phys chunk = row*4 + (q ^ ((row>>1)&3))
    __shared__ ushort Bl[128 * 32];   // 8 KB
    const int tid = threadIdx.x, lane = tid & 63, wave = tid >> 6;
    const int bm = blockIdx.x * 128, bn = blockIdx.y * 128;

    // staging source/dest precompute (advance sources by BK each iter)
    const uint* agp[4]; const uint* alp[4];
    #pragma unroll
    for (int s = 0; s < 4; ++s) {
        int t = wave * 4 + s;
        int p = t * 64 + lane;           // physical chunk 0..1023
        int row = p >> 3, cs = p & 7;
        int c = cs ^ (row & 7);          // global k-chunk (4 u32 each)
        int grow = bm + row; if (grow > M - 1) grow = M - 1;
        agp[s] = xp + ((size_t)grow * 512 + c * 4);
        alp[s] = &As[t * 256];           // wave-uniform LDS base; HW adds lane*16B
    }
    const ushort* bhgp[2]; const ushort* blgp[2]; const ushort* bhlp[2]; const ushort* bllp[2];
    #pragma unroll
    for (int s = 0; s < 2; ++s) {
        int t = wave * 2 + s;
        int p = t * 64 + lane;           // physical chunk 0..511
        int row = p >> 2, qs = p & 3;
        int q = qs ^ ((row >> 1) & 3);   // global k-chunk (8 bf16 each)
        size_t go = (size_t)(bn + row) * 512 + q * 8;
        bhgp[s] = bhi + go; blgp[s] = blo + go;
        bhlp[s] = &Bh[t * 512]; bllp[s] = &Bl[t * 512];
    }

    f32x4 acc[4][4] = {};
    const int wm = (wave >> 1) * 64, wn = (wave & 1) * 64;
    const int fm = lane & 15, quad = lane >> 4;

    for (int kk = 0; kk < 16; ++kk) {
        #pragma unroll
        for (int s = 0; s < 4; ++s) GLOBAL_LOAD_LDS16(agp[s], alp[s]);
        #pragma unroll
        for (int s = 0; s < 2; ++s) {
            GLOBAL_LOAD_LDS16(bhgp[s], bhlp[s]);
            GLOBAL_LOAD_LDS16(blgp[s], bllp[s]);
        }
        #pragma unroll
        for (int s = 0; s < 4; ++s) agp[s] += 32;
        #pragma unroll
        for (int s = 0; s < 2; ++s) { bhgp[s] += 32; blgp[s] += 32; }
        __syncthreads();   // drains vmcnt: staged data visible

        bf16x8 ah[4], al[4], bh[4], bl[4];
        #pragma unroll
        for (int i = 0; i < 4; ++i) {
            int row = wm + i * 16 + fm;
            int sw = row & 7;
            uint4 c0 = *(const uint4*)&As[row * 32 + (((2 * quad)     ^ sw) * 4)];
            uint4 c1 = *(const uint4*)&As[row * 32 + (((2 * quad + 1) ^ sw) * 4)];
            union { uint u[4]; bf16x8 v; } H, L;
            H.u[0] = __builtin_amdgcn_perm(c0.y, c0.x, 0x07060302u);
            H.u[1] = __builtin_amdgcn_perm(c0.w, c0.z, 0x07060302u);
            H.u[2] = __builtin_amdgcn_perm(c1.y, c1.x, 0x07060302u);
            H.u[3] = __builtin_amdgcn_perm(c1.w, c1.z, 0x07060302u);
            L.u[0] = __builtin_amdgcn_perm(c0.y, c0.x, 0x05040100u);
            L.u[1] = __builtin_amdgcn_perm(c0.w, c0.z, 0x05040100u);
            L.u[2] = __builtin_amdgcn_perm(c1.y, c1.x, 0x05040100u);
            L.u[3] = __builtin_amdgcn_perm(c1.w, c1.z, 0x05040100u);
            ah[i] = H.v; al[i] = L.v;
        }
        #pragma unroll
        for (int j = 0; j < 4; ++j) {
            int row = wn + j * 16 + fm;
            int qs = quad ^ ((row >> 1) & 3);
            bh[j] = *(const bf16x8*)&Bh[row * 32 + qs * 8];
            bl[j] = *(const bf16x8*)&Bl[row * 32 + qs * 8];
        }
        #pragma unroll
        for (int i = 0; i < 4; ++i)
            #pragma unroll
            for (int j = 0; j < 4; ++j) {
                acc[i][j] = __builtin_amdgcn_mfma_f32_16x16x32_bf16(ah[i], bh[j], acc[i][j], 0, 0, 0);
                acc[i][j] = __builtin_amdgcn_mfma_f32_16x16x32_bf16(ah[i], bl[j], acc[i][j], 0, 0, 0);
                acc[i][j] = __builtin_amdgcn_mfma_f32_16x16x32_bf16(al[i], bh[j], acc[i][j], 0, 0, 0);
            }
        __syncthreads();
    }

    // epilogue: C/D layout col=lane&15, row=quad*4+reg (m89-verified)
    #pragma unroll
    for (int i = 0; i < 4; ++i) {
        int rb = bm + wm + i * 16 + quad * 4;
        #pragma unroll
        for (int j = 0; j < 4; ++j) {
            int col = bn + wn + j * 16 + fm;
            #pragma unroll
            for (int r = 0; r < 4; ++r) {
                int row = rb + r;
                if (row < M) C[(size_t)row * 256 + col] = acc[i][j][r];
            }
        }
    }
}

// ---------------------------------------------------------------- CSR build
__global__ void count_deg(const int* __restrict__ ei, int* __restrict__ deg) {
    int e = blockIdx.x * blockDim.x + threadIdx.x;
    if (e >= E2) return;
    int dst = (e < N_EDGES) ? ei[N_EDGES + e] : (e - N_EDGES);
    atomicAdd(&deg[dst], 1);
}

#define SCAN_B 256
#define SCAN_NB ((N_NODES + SCAN_B - 1) / SCAN_B)   // 196

__global__ void scan1_kernel(const int* __restrict__ deg, int* __restrict__ rowstart,
                             int* __restrict__ blocksum) {
    __shared__ int sm[SCAN_B];
    int t = threadIdx.x, i = blockIdx.x * SCAN_B + t;
    int v = (i < N_NODES) ? deg[i] : 0;
    sm[t] = v; __syncthreads();
    int x = v;
    for (int off = 1; off < SCAN_B; off <<= 1) {
        int y = (t >= off) ? sm[t - off] : 0; __syncthreads();
        x += y; sm[t] = x; __syncthreads();
    }
    if (i < N_NODES) rowstart[i] = x - v;
    if (t == SCAN_B - 1) blocksum[blockIdx.x] = x;
}

__global__ void scan2_kernel(const int* __restrict__ blocksum, int* __restrict__ blockoff,
                             int* __restrict__ rowstart) {
    __shared__ int sm[256];
    int t = threadIdx.x;
    int v = (t < SCAN_NB) ? blocksum[t] : 0;
    sm[t] = v; __syncthreads();
    int x = v;
    for (int off = 1; off < 256; off <<= 1) {
        int y = (t >= off) ? sm[t - off] : 0; __syncthreads();
        x += y; sm[t] = x; __syncthreads();
    }
    if (t < SCAN_NB) blockoff[t] = x - v;
    if (t == 255) rowstart[N_NODES] = x;
}

__global__ void scan3_kernel(int* __restrict__ rowstart, const int* __restrict__ blockoff) {
    int i = blockIdx.x * 256 + threadIdx.x;
    if (i < N_NODES) rowstart[i] += blockoff[i >> 8];
}

__global__ void fill_csr(const int* __restrict__ ei, const int* __restrict__ rowstart,
                         int* __restrict__ cursor, int* __restrict__ csr_src) {
    int e = blockIdx.x * blockDim.x + threadIdx.x;
    if (e >= E2) return;
    int src, dst;
    if (e < N_EDGES) { src = ei[e]; dst = ei[N_EDGES + e]; }
    else             { src = e - N_EDGES; dst = src; }
    int p = atomicAdd(&cursor[dst], 1);
    csr_src[rowstart[dst] + p] = src;
}

// ---------------------------------------------------------------- fp32 GEMM small-N (layer 2)
template<int BM, int BN, int BK, int TM, int TN, int K, int NOUT>
__global__ void __launch_bounds__(256) gemm_kernel(const float* __restrict__ A,
                                                   const float* __restrict__ B,
                                                   float* __restrict__ C, int M) {
    __shared__ float As[BK][BM];
    __shared__ float Bs[BK][BN];
    const int tid = threadIdx.x;
    const int bm = blockIdx.x * BM;
    const int bn = blockIdx.y * BN;
    constexpr int TX = BN / TN;
    const int tx = tid % TX;
    const int ty = tid / TX;
    float acc[TM][TN] = {};
    constexpr int A4 = BM * BK / 4;
    constexpr int AR = BK / 4;
    constexpr int B4 = BK * BN / 4;
    constexpr int BR = BN / 4;

    for (int k0 = 0; k0 < K; k0 += BK) {
        for (int i = tid; i < A4; i += 256) {
            int row = i / AR;
            int kc  = (i % AR) * 4;
            float4 v = make_float4(0.f, 0.f, 0.f, 0.f);
            int grow = bm + row;
            if (grow < M) v = *(const float4*)(A + (size_t)grow * K + k0 + kc);
            As[kc + 0][row] = v.x; As[kc + 1][row] = v.y;
            As[kc + 2][row] = v.z; As[kc + 3][row] = v.w;
        }
        for (int i = tid; i < B4; i += 256) {
            int row = i / BR;
            int nc  = (i % BR) * 4;
            *(float4*)&Bs[row][nc] = *(const float4*)(B + (size_t)(k0 + row) * NOUT + bn + nc);
        }
        __syncthreads();
        #pragma unroll
        for (int k = 0; k < BK; ++k) {
            float af[TM], bf[TN];
            #pragma unroll
            for (int i = 0; i < TM; ++i) af[i] = As[k][ty * TM + i];
            #pragma unroll
            for (int j = 0; j < TN; ++j) bf[j] = Bs[k][tx * TN + j];
            #pragma unroll
            for (int i = 0; i < TM; ++i)
                #pragma unroll
                for (int j = 0; j < TN; ++j)
                    acc[i][j] += af[i] * bf[j];
        }
        __syncthreads();
    }
    #pragma unroll
    for (int i = 0; i < TM; ++i) {
        int grow = bm + ty * TM + i;
        if (grow >= M) continue;
        float* cp = C + (size_t)grow * NOUT + bn + tx * TN;
        if (TN == 4)      *(float4*)cp = make_float4(acc[i][0], acc[i][1], acc[i][2], acc[i][3]);
        else if (TN == 2) *(float2*)cp = make_float2(acc[i][0], acc[i][1]);
        else for (int j = 0; j < TN; ++j) cp[j] = acc[i][j];
    }
}

// ---------------------------------------------------------------- scores
__global__ void scores1_kernel(const float* __restrict__ h, const float* __restrict__ asrc,
                               const float* __restrict__ adst,
                               float* __restrict__ ssrc, float* __restrict__ sdst) {
    int gid = blockIdx.x * blockDim.x + threadIdx.x;
    int n = gid >> 3, hh = gid & 7;
    if (n >= N_NODES) return;
    const float* hp = h + (size_t)n * HC + hh * HID;
    const float* as = asrc + hh * HID;
    const float* ad = adst + hh * HID;
    float s1 = 0.f, s2 = 0.f;
    #pragma unroll
    for (int c = 0; c < HID; ++c) { float v = hp[c]; s1 += v * as[c]; s2 += v * ad[c]; }
    ssrc[n * HEADS + hh] = s1;
    sdst[n * HEADS + hh] = s2;
}

__global__ void scores2_kernel(const float* __restrict__ h2, const float* __restrict__ asrc,
                               const float* __restrict__ adst,
                               float* __restrict__ ssrc, float* __restrict__ sdst) {
    int n = blockIdx.x * blockDim.x + threadIdx.x;
    if (n >= N_NODES) return;
    float s1 = 0.f, s2 = 0.f;
    #pragma unroll
    for (int c = 0; c < NCLASS; ++c) {
        float v = h2[(size_t)n * NCLASS + c];
        s1 += v * asrc[c]; s2 += v * adst[c];
    }
    ssrc[n] = s1; sdst[n] = s2;
}

// ---------------------------------------------------------------- layer-1 aggregation
__global__ void __launch_bounds__(256) agg1_wave_kernel(const float* __restrict__ h,
        const float* __restrict__ ssrc, const float* __restrict__ sdst,
        const int* __restrict__ rowstart, const int* __restrict__ csr_src,
        const float* __restrict__ bias, float* __restrict__ out) {
    const int wid = (blockIdx.x * blockDim.x + threadIdx.x) >> 6;   // node id
    if (wid >= N_NODES) return;
    const int lane = threadIdx.x & 63;
    const int hg = lane >> 3;
    const int hl = lane & 7;
    const int n = wid;
    const int beg = rowstart[n], end = rowstart[n + 1];
    const float sdst_n = sdst[(size_t)n * HEADS + hg];

    float m = -INFINITY, s = 0.f;
    for (int e = beg + hl; e < end; e += 8) {
        int src = csr_src[e];
        float sc = ssrc[(size_t)src * HEADS + hg] + sdst_n;
        sc = sc > 0.f ? sc : NEG_SLOPE * sc;
        float nm = fmaxf(m, sc);
        s = s * __expf(m - nm) + __expf(sc - nm);
        m = nm;
    }
    #pragma unroll
    for (int off = 4; off > 0; off >>= 1) {
        float om = __shfl_xor(m, off);
        float os = __shfl_xor(s, off);
        float nm = fmaxf(m, om);
        float a = (m  == -INFINITY) ? 0.f : s  * __expf(m  - nm);
        float b = (om == -INFINITY) ? 0.f : os * __expf(om - nm);
        m = nm; s = a + b;
    }

    float4 acc = make_float4(0.f, 0.f, 0.f, 0.f);
    const float* hc = h + (size_t)lane * 4;
    int e = beg;
    for (; e + 1 < end; e += 2) {
        int s0 = csr_src[e], s1 = csr_src[e + 1];
        float x0 = ssrc[(size_t)s0 * HEADS + hg] + sdst_n;
        float x1 = ssrc[(size_t)s1 * HEADS + hg] + sdst_n;
        float4 h0 = *(const float4*)(hc + (size_t)s0 * HC);
        float4 h1 = *(const float4*)(hc + (size_t)s1 * HC);
        x0 = x0 > 0.f ? x0 : NEG_SLOPE * x0;
        x1 = x1 > 0.f ? x1 : NEG_SLOPE * x1;
        float w0 = __expf(x0 - m), w1 = __expf(x1 - m);
        acc.x += w0 * h0.x + w1 * h1.x;
        acc.y += w0 * h0.y + w1 * h1.y;
        acc.z += w0 * h0.z + w1 * h1.z;
        acc.w += w0 * h0.w + w1 * h1.w;
    }
    if (e < end) {
        int s0 = csr_src[e];
        float x0 = ssrc[(size_t)s0 * HEADS + hg] + sdst_n;
        x0 = x0 > 0.f ? x0 : NEG_SLOPE * x0;
        float w0 = __expf(x0 - m);
        float4 h0 = *(const float4*)(hc + (size_t)s0 * HC);
        acc.x += w0 * h0.x; acc.y += w0 * h0.y;
        acc.z += w0 * h0.z; acc.w += w0 * h0.w;
    }
    float inv = 1.f / (s + 1e-16f);
    float4 bv = *(const float4*)(bias + lane * 4);
    float4 o;
    o.x = acc.x * inv + bv.x; o.y = acc.y * inv + bv.y;
    o.z = acc.z * inv + bv.z; o.w = acc.w * inv + bv.w;
    o.x = o.x > 0.f ? o.x : expm1f(o.x);
    o.y = o.y > 0.f ? o.y : expm1f(o.y);
    o.z = o.z > 0.f ? o.z : expm1f(o.z);
    o.w = o.w > 0.f ? o.w : expm1f(o.w);
    *(float4*)(out + (size_t)n * HC + lane * 4) = o;
}

// ---------------------------------------------------------------- layer-2 aggregation
__global__ void __launch_bounds__(64) agg2_kernel(const float* __restrict__ h2,
        const float* __restrict__ ssrc, const float* __restrict__ sdst,
        const int* __restrict__ rowstart, const int* __restrict__ csr_src,
        const float* __restrict__ bias, float* __restrict__ out) {
    const int n = blockIdx.x;
    const int beg = rowstart[n], end = rowstart[n + 1];
    const int t = threadIdx.x;
    const float sdst_n = sdst[n];

    float m = -INFINITY, s = 0.f;
    for (int e = beg + t; e < end; e += 64) {
        float sc = ssrc[csr_src[e]] + sdst_n;
        sc = sc > 0.f ? sc : NEG_SLOPE * sc;
        float nm = fmaxf(m, sc);
        s = s * __expf(m - nm) + __expf(sc - nm);
        m = nm;
    }
    #pragma unroll
    for (int off = 32; off > 0; off >>= 1) {
        float om = __shfl_xor(m, off);
        float os = __shfl_xor(s, off);
        float nm = fmaxf(m, om);
        float a = (m  == -INFINITY) ? 0.f : s  * __expf(m  - nm);
        float b = (om == -INFINITY) ? 0.f : os * __expf(om - nm);
        m = nm; s = a + b;
    }
    const int c = t & 31, half = t >> 5;
    float acc = 0.f;
    for (int e = beg + half; e < end; e += 2) {
        int src = csr_src[e];
        float sc = ssrc[src] + sdst_n;
        sc = sc > 0.f ? sc : NEG_SLOPE * sc;
        acc += __expf(sc - m) * h2[(size_t)src * NCLASS + c];
    }
    acc += __shfl_down(acc, 32);
    if (t < 32) out[(size_t)n * NCLASS + c] = acc / (s + 1e-16f) + bias[c] + 1e-6f;
}

// ---------------------------------------------------------------- launcher
extern "C" void kernel_launch(void* const* d_in, const int* in_sizes, int n_in,
                              void* d_out, int out_size, void* d_ws, size_t ws_size,
                              hipStream_t stream) {
    float*       x        = (float*)      d_in[0];   // repacked in place (restored each call)
    const int*   ei       = (const int*)  d_in[1];
    const float* W1       = (const float*)d_in[2];
    const float* att_src1 = (const float*)d_in[3];
    const float* att_dst1 = (const float*)d_in[4];
    const float* b1       = (const float*)d_in[5];
    const float* W2       = (const float*)d_in[6];
    const float* att_src2 = (const float*)d_in[7];
    const float* att_dst2 = (const float*)d_in[8];
    const float* b2       = (const float*)d_in[9];
    float* out = (float*)d_out;

    // workspace layout (w1t first for 16B alignment of bf16 staging)
    ushort* w1t_hi = (ushort*)d_ws;                        // 256*512
    ushort* w1t_lo = w1t_hi + 256 * 512;                   // 256*512
    float* h1    = (float*)(w1t_lo + 256 * 512);           // N*HC
    float* out1  = h1 + (size_t)N_NODES * HC;              // N*HC
    float* h2    = out1 + (size_t)N_NODES * HC;            // N*NCLASS
    float* ssrc1 = h2 + (size_t)N_NODES * NCLASS;          // N*HEADS
    float* sdst1 = ssrc1 + (size_t)N_NODES * HEADS;        // N*HEADS
    float* ssrc2 = sdst1 + (size_t)N_NODES * HEADS;        // N
    float* sdst2 = ssrc2 + N_NODES;                        // N
    int* rowstart = (int*)(sdst2 + N_NODES);               // N+1
    int* deg      = rowstart + N_NODES + 1;                // N
    int* cursor   = deg + N_NODES;                         // N
    int* csr_src  = cursor + N_NODES;                      // E2
    int* blocksum = csr_src + E2;                          // SCAN_NB
    int* blockoff = blocksum + SCAN_NB;                    // SCAN_NB

    // CSR build
    hipMemsetAsync(deg, 0, N_NODES * sizeof(int), stream);
    hipMemsetAsync(cursor, 0, N_NODES * sizeof(int), stream);
    int eb = (E2 + 255) / 256;
    count_deg<<<eb, 256, 0, stream>>>(ei, deg);
    scan1_kernel<<<SCAN_NB, SCAN_B, 0, stream>>>(deg, rowstart, blocksum);
    scan2_kernel<<<1, 256, 0, stream>>>(blocksum, blockoff, rowstart);
    scan3_kernel<<<SCAN_NB, SCAN_B, 0, stream>>>(rowstart, blockoff);
    fill_csr<<<eb, 256, 0, stream>>>(ei, rowstart, cursor, csr_src);

    // precision split
    split_x_kernel<<<(N_NODES * F_IN / 4) / 256, 256, 0, stream>>>(x);
    split_w1t_kernel<<<(256 * 512) / 256, 256, 0, stream>>>(W1, w1t_hi, w1t_lo);

    // layer 1: MFMA GEMM
    {
        dim3 grid((N_NODES + 127) / 128, HC / 128);
        gemm1_mfma_kernel<<<grid, 256, 0, stream>>>((const uint*)x, w1t_hi, w1t_lo, h1, N_NODES);
    }
    scores1_kernel<<<(N_NODES * HEADS + 255) / 256, 256, 0, stream>>>(h1, att_src1, att_dst1, ssrc1, sdst1);
    agg1_wave_kernel<<<(N_NODES + 3) / 4, 256, 0, stream>>>(h1, ssrc1, sdst1, rowstart, csr_src, b1, out1);

    // layer 2
    {
        dim3 grid((N_NODES + 63) / 64, NCLASS / 32);
        gemm_kernel<64, 32, 16, 4, 2, HC, NCLASS><<<grid, 256, 0, stream>>>(out1, W2, h2, N_NODES);
    }
    scores2_kernel<<<(N_NODES + 255) / 256, 256, 0, stream>>>(h2, att_src2, att_dst2, ssrc2, sdst2);
    agg2_kernel<<<N_NODES, 64, 0, stream>>>(h2, ssrc2, sdst2, rowstart, csr_src, b2, out);
}

// Round 4
// 498.742 us; speedup vs baseline: 1.5770x; 1.1254x over previous
//
#include <hip/hip_runtime.h>
#include <math.h>

#define N_NODES 50000
#define N_EDGES 800000
#define E2 (N_EDGES + N_NODES)   // with self loops
#define F_IN 512
#define HEADS 8
#define HID 32
#define HC 256                    // HEADS*HID
#define NCLASS 32
#define NEG_SLOPE 0.2f

typedef unsigned int uint;
typedef unsigned short ushort;
typedef __attribute__((ext_vector_type(8))) short bf16x8;   // 8 bf16 (4 VGPRs)
typedef __attribute__((ext_vector_type(4))) float f32x4;

#define GLOBAL_LOAD_LDS16(g, l) \
    __builtin_amdgcn_global_load_lds((const __attribute__((address_space(1))) void*)(g), \
                                     (__attribute__((address_space(3))) void*)(l), 16, 0, 0)

__device__ inline uint bf16_rne_bits(float f) {
    uint u = __float_as_uint(f);
    return (u + 0x7fffu + ((u >> 16) & 1u)) >> 16;
}
__device__ inline float bf2f(ushort u) { return __uint_as_float(((uint)u) << 16); }

// ------------------------------------------------ split x in place: fp32 -> (hi<<16)|lo
__global__ void split_x_kernel(float* __restrict__ x) {
    size_t i = ((size_t)blockIdx.x * blockDim.x + threadIdx.x) * 4;  // 25.6M elems, /4 exact
    float4 v = *(float4*)(x + i);
    uint4 p;
    {
        uint h = bf16_rne_bits(v.x); float r = v.x - __uint_as_float(h << 16);
        p.x = (h << 16) | bf16_rne_bits(r);
    }
    {
        uint h = bf16_rne_bits(v.y); float r = v.y - __uint_as_float(h << 16);
        p.y = (h << 16) | bf16_rne_bits(r);
    }
    {
        uint h = bf16_rne_bits(v.z); float r = v.z - __uint_as_float(h << 16);
        p.z = (h << 16) | bf16_rne_bits(r);
    }
    {
        uint h = bf16_rne_bits(v.w); float r = v.w - __uint_as_float(h << 16);
        p.w = (h << 16) | bf16_rne_bits(r);
    }
    *(uint4*)(x + i) = p;
}

// ------------------------------------------------ W1 [512][256] -> W1^T hi/lo bf16 [256][512]
__global__ void split_w1t_kernel(const float* __restrict__ W1,
                                 ushort* __restrict__ hi, ushort* __restrict__ lo) {
    int t = blockIdx.x * 256 + threadIdx.x;      // t = n*512 + k, t < 131072
    int n = t >> 9, k = t & 511;
    float f = W1[k * 256 + n];
    uint h = bf16_rne_bits(f);
    float r = f - __uint_as_float(h << 16);
    hi[t] = (ushort)h;
    lo[t] = (ushort)bf16_rne_bits(r);
}

// ------------------------------------------------ MFMA GEMM1: h1b[M,256] = x @ W1 (split bf16, 3-term)
// xp: [M][512] packed hi|lo u32; bhi/blo: [256][512] bf16 (W1^T); output bf16
__global__ void __launch_bounds__(256) gemm1_mfma_kernel(const uint* __restrict__ xp,
        const ushort* __restrict__ bhi, const ushort* __restrict__ blo,
        ushort* __restrict__ C, int M) {
    __shared__ uint   As[128 * 32];   // 16 KB packed, chunk-swizzled: phys chunk = row*8 + (c ^ (row&7))
    __shared__ ushort Bh[128 * 32];   // 8 KB,  phys chunk = row*4 + (q ^ ((row>>1)&3))
    __shared__ ushort Bl[128 * 32];   // 8 KB
    const int tid = threadIdx.x, lane = tid & 63, wave = tid >> 6;
    const int bm = blockIdx.x * 128, bn = blockIdx.y * 128;

    const uint* agp[4]; const uint* alp[4];
    #pragma unroll
    for (int s = 0; s < 4; ++s) {
        int t = wave * 4 + s;
        int p = t * 64 + lane;           // physical chunk 0..1023
        int row = p >> 3, cs = p & 7;
        int c = cs ^ (row & 7);          // global k-chunk (4 u32 each)
        int grow = bm + row; if (grow > M - 1) grow = M - 1;
        agp[s] = xp + ((size_t)grow * 512 + c * 4);
        alp[s] = &As[t * 256];           // wave-uniform LDS base; HW adds lane*16B
    }
    const ushort* bhgp[2]; const ushort* blgp[2]; const ushort* bhlp[2]; const ushort* bllp[2];
    #pragma unroll
    for (int s = 0; s < 2; ++s) {
        int t = wave * 2 + s;
        int p = t * 64 + lane;           // physical chunk 0..511
        int row = p >> 2, qs = p & 3;
        int q = qs ^ ((row >> 1) & 3);   // global k-chunk (8 bf16 each)
        size_t go = (size_t)(bn + row) * 512 + q * 8;
        bhgp[s] = bhi + go; blgp[s] = blo + go;
        bhlp[s] = &Bh[t * 512]; bllp[s] = &Bl[t * 512];
    }

    f32x4 acc[4][4] = {};
    const int wm = (wave >> 1) * 64, wn = (wave & 1) * 64;
    const int fm = lane & 15, quad = lane >> 4;

    for (int kk = 0; kk < 16; ++kk) {
        #pragma unroll
        for (int s = 0; s < 4; ++s) GLOBAL_LOAD_LDS16(agp[s], alp[s]);
        #pragma unroll
        for (int s = 0; s < 2; ++s) {
            GLOBAL_LOAD_LDS16(bhgp[s], bhlp[s]);
            GLOBAL_LOAD_LDS16(blgp[s], bllp[s]);
        }
        #pragma unroll
        for (int s = 0; s < 4; ++s) agp[s] += 32;
        #pragma unroll
        for (int s = 0; s < 2; ++s) { bhgp[s] += 32; blgp[s] += 32; }
        __syncthreads();

        bf16x8 ah[4], al[4], bh[4], bl[4];
        #pragma unroll
        for (int i = 0; i < 4; ++i) {
            int row = wm + i * 16 + fm;
            int sw = row & 7;
            uint4 c0 = *(const uint4*)&As[row * 32 + (((2 * quad)     ^ sw) * 4)];
            uint4 c1 = *(const uint4*)&As[row * 32 + (((2 * quad + 1) ^ sw) * 4)];
            union { uint u[4]; bf16x8 v; } H, L;
            H.u[0] = __builtin_amdgcn_perm(c0.y, c0.x, 0x07060302u);
            H.u[1] = __builtin_amdgcn_perm(c0.w, c0.z, 0x07060302u);
            H.u[2] = __builtin_amdgcn_perm(c1.y, c1.x, 0x07060302u);
            H.u[3] = __builtin_amdgcn_perm(c1.w, c1.z, 0x07060302u);
            L.u[0] = __builtin_amdgcn_perm(c0.y, c0.x, 0x05040100u);
            L.u[1] = __builtin_amdgcn_perm(c0.w, c0.z, 0x05040100u);
            L.u[2] = __builtin_amdgcn_perm(c1.y, c1.x, 0x05040100u);
            L.u[3] = __builtin_amdgcn_perm(c1.w, c1.z, 0x05040100u);
            ah[i] = H.v; al[i] = L.v;
        }
        #pragma unroll
        for (int j = 0; j < 4; ++j) {
            int row = wn + j * 16 + fm;
            int qs = quad ^ ((row >> 1) & 3);
            bh[j] = *(const bf16x8*)&Bh[row * 32 + qs * 8];
            bl[j] = *(const bf16x8*)&Bl[row * 32 + qs * 8];
        }
        #pragma unroll
        for (int i = 0; i < 4; ++i)
            #pragma unroll
            for (int j = 0; j < 4; ++j) {
                acc[i][j] = __builtin_amdgcn_mfma_f32_16x16x32_bf16(ah[i], bh[j], acc[i][j], 0, 0, 0);
                acc[i][j] = __builtin_amdgcn_mfma_f32_16x16x32_bf16(ah[i], bl[j], acc[i][j], 0, 0, 0);
                acc[i][j] = __builtin_amdgcn_mfma_f32_16x16x32_bf16(al[i], bh[j], acc[i][j], 0, 0, 0);
            }
        __syncthreads();
    }

    // epilogue: C/D layout col=lane&15, row=quad*4+reg (m89-verified); write bf16
    #pragma unroll
    for (int i = 0; i < 4; ++i) {
        int rb = bm + wm + i * 16 + quad * 4;
        #pragma unroll
        for (int j = 0; j < 4; ++j) {
            int col = bn + wn + j * 16 + fm;
            #pragma unroll
            for (int r = 0; r < 4; ++r) {
                int row = rb + r;
                if (row < M) C[(size_t)row * 256 + col] = (ushort)bf16_rne_bits(acc[i][j][r]);
            }
        }
    }
}

// ---------------------------------------------------------------- CSR build
__global__ void count_deg(const int* __restrict__ ei, int* __restrict__ deg) {
    int e = blockIdx.x * blockDim.x + threadIdx.x;
    if (e >= E2) return;
    int dst = (e < N_EDGES) ? ei[N_EDGES + e] : (e - N_EDGES);
    atomicAdd(&deg[dst], 1);
}

#define SCAN_B 256
#define SCAN_NB ((N_NODES + SCAN_B - 1) / SCAN_B)   // 196

__global__ void scan1_kernel(const int* __restrict__ deg, int* __restrict__ rowstart,
                             int* __restrict__ blocksum) {
    __shared__ int sm[SCAN_B];
    int t = threadIdx.x, i = blockIdx.x * SCAN_B + t;
    int v = (i < N_NODES) ? deg[i] : 0;
    sm[t] = v; __syncthreads();
    int x = v;
    for (int off = 1; off < SCAN_B; off <<= 1) {
        int y = (t >= off) ? sm[t - off] : 0; __syncthreads();
        x += y; sm[t] = x; __syncthreads();
    }
    if (i < N_NODES) rowstart[i] = x - v;
    if (t == SCAN_B - 1) blocksum[blockIdx.x] = x;
}

__global__ void scan2_kernel(const int* __restrict__ blocksum, int* __restrict__ blockoff,
                             int* __restrict__ rowstart) {
    __shared__ int sm[256];
    int t = threadIdx.x;
    int v = (t < SCAN_NB) ? blocksum[t] : 0;
    sm[t] = v; __syncthreads();
    int x = v;
    for (int off = 1; off < 256; off <<= 1) {
        int y = (t >= off) ? sm[t - off] : 0; __syncthreads();
        x += y; sm[t] = x; __syncthreads();
    }
    if (t < SCAN_NB) blockoff[t] = x - v;
    if (t == 255) rowstart[N_NODES] = x;
}

__global__ void scan3_kernel(int* __restrict__ rowstart, const int* __restrict__ blockoff) {
    int i = blockIdx.x * 256 + threadIdx.x;
    if (i < N_NODES) rowstart[i] += blockoff[i >> 8];
}

__global__ void fill_csr(const int* __restrict__ ei, const int* __restrict__ rowstart,
                         int* __restrict__ cursor, int* __restrict__ csr_src) {
    int e = blockIdx.x * blockDim.x + threadIdx.x;
    if (e >= E2) return;
    int src, dst;
    if (e < N_EDGES) { src = ei[e]; dst = ei[N_EDGES + e]; }
    else             { src = e - N_EDGES; dst = src; }
    int p = atomicAdd(&cursor[dst], 1);
    csr_src[rowstart[dst] + p] = src;
}

// ---------------------------------------------------------------- fp32 GEMM small-N (layer 2), bf16 out
template<int BM, int BN, int BK, int TM, int TN, int K, int NOUT>
__global__ void __launch_bounds__(256) gemm_bf16out_kernel(const float* __restrict__ A,
                                                           const float* __restrict__ B,
                                                           ushort* __restrict__ C, int M) {
    __shared__ float As[BK][BM];
    __shared__ float Bs[BK][BN];
    const int tid = threadIdx.x;
    const int bm = blockIdx.x * BM;
    const int bn = blockIdx.y * BN;
    constexpr int TX = BN / TN;
    const int tx = tid % TX;
    const int ty = tid / TX;
    float acc[TM][TN] = {};
    constexpr int A4 = BM * BK / 4;
    constexpr int AR = BK / 4;
    constexpr int B4 = BK * BN / 4;
    constexpr int BR = BN / 4;

    for (int k0 = 0; k0 < K; k0 += BK) {
        for (int i = tid; i < A4; i += 256) {
            int row = i / AR;
            int kc  = (i % AR) * 4;
            float4 v = make_float4(0.f, 0.f, 0.f, 0.f);
            int grow = bm + row;
            if (grow < M) v = *(const float4*)(A + (size_t)grow * K + k0 + kc);
            As[kc + 0][row] = v.x; As[kc + 1][row] = v.y;
            As[kc + 2][row] = v.z; As[kc + 3][row] = v.w;
        }
        for (int i = tid; i < B4; i += 256) {
            int row = i / BR;
            int nc  = (i % BR) * 4;
            *(float4*)&Bs[row][nc] = *(const float4*)(B + (size_t)(k0 + row) * NOUT + bn + nc);
        }
        __syncthreads();
        #pragma unroll
        for (int k = 0; k < BK; ++k) {
            float af[TM], bf[TN];
            #pragma unroll
            for (int i = 0; i < TM; ++i) af[i] = As[k][ty * TM + i];
            #pragma unroll
            for (int j = 0; j < TN; ++j) bf[j] = Bs[k][tx * TN + j];
            #pragma unroll
            for (int i = 0; i < TM; ++i)
                #pragma unroll
                for (int j = 0; j < TN; ++j)
                    acc[i][j] += af[i] * bf[j];
        }
        __syncthreads();
    }
    #pragma unroll
    for (int i = 0; i < TM; ++i) {
        int grow = bm + ty * TM + i;
        if (grow >= M) continue;
        ushort* cp = C + (size_t)grow * NOUT + bn + tx * TN;
        static_assert(TN == 2, "bf16 out pack assumes TN==2");
        uint pk = bf16_rne_bits(acc[i][0]) | (bf16_rne_bits(acc[i][1]) << 16);
        *(uint*)cp = pk;
    }
}

// ---------------------------------------------------------------- scores (bf16 inputs)
__global__ void scores1_kernel(const ushort* __restrict__ h, const float* __restrict__ asrc,
                               const float* __restrict__ adst,
                               float* __restrict__ ssrc, float* __restrict__ sdst) {
    int gid = blockIdx.x * blockDim.x + threadIdx.x;
    int n = gid >> 3, hh = gid & 7;
    if (n >= N_NODES) return;
    const uint* hp = (const uint*)(h + (size_t)n * HC + hh * HID);  // 16 uints = 32 bf16
    const float* as = asrc + hh * HID;
    const float* ad = adst + hh * HID;
    float s1 = 0.f, s2 = 0.f;
    #pragma unroll
    for (int q = 0; q < 4; ++q) {
        uint4 u = ((const uint4*)hp)[q];
        uint w[4] = {u.x, u.y, u.z, u.w};
        #pragma unroll
        for (int k = 0; k < 4; ++k) {
            int c = q * 8 + k * 2;
            float v0 = __uint_as_float(w[k] << 16);
            float v1 = __uint_as_float(w[k] & 0xffff0000u);
            s1 += v0 * as[c] + v1 * as[c + 1];
            s2 += v0 * ad[c] + v1 * ad[c + 1];
        }
    }
    ssrc[n * HEADS + hh] = s1;
    sdst[n * HEADS + hh] = s2;
}

__global__ void scores2_kernel(const ushort* __restrict__ h2, const float* __restrict__ asrc,
                               const float* __restrict__ adst,
                               float* __restrict__ ssrc, float* __restrict__ sdst) {
    int n = blockIdx.x * blockDim.x + threadIdx.x;
    if (n >= N_NODES) return;
    const uint* hp = (const uint*)(h2 + (size_t)n * NCLASS);
    float s1 = 0.f, s2 = 0.f;
    #pragma unroll
    for (int q = 0; q < 4; ++q) {
        uint4 u = ((const uint4*)hp)[q];
        uint w[4] = {u.x, u.y, u.z, u.w};
        #pragma unroll
        for (int k = 0; k < 4; ++k) {
            int c = q * 8 + k * 2;
            float v0 = __uint_as_float(w[k] << 16);
            float v1 = __uint_as_float(w[k] & 0xffff0000u);
            s1 += v0 * asrc[c] + v1 * asrc[c + 1];
            s2 += v0 * adst[c] + v1 * adst[c + 1];
        }
    }
    ssrc[n] = s1; sdst[n] = s2;
}

// ---------------------------------------------------------------- layer-1 aggregation (bf16 gather)
__global__ void __launch_bounds__(256) agg1_wave_kernel(const ushort* __restrict__ h,
        const float* __restrict__ ssrc, const float* __restrict__ sdst,
        const int* __restrict__ rowstart, const int* __restrict__ csr_src,
        const float* __restrict__ bias, float* __restrict__ out) {
    const int wid = (blockIdx.x * blockDim.x + threadIdx.x) >> 6;   // node id
    if (wid >= N_NODES) return;
    const int lane = threadIdx.x & 63;
    const int hg = lane >> 3;
    const int hl = lane & 7;
    const int n = wid;
    const int beg = rowstart[n], end = rowstart[n + 1];
    const float sdst_n = sdst[(size_t)n * HEADS + hg];

    // phase 1: per-head online softmax, 8 lanes per head
    float m = -INFINITY, s = 0.f;
    for (int e = beg + hl; e < end; e += 8) {
        int src = csr_src[e];
        float sc = ssrc[(size_t)src * HEADS + hg] + sdst_n;
        sc = sc > 0.f ? sc : NEG_SLOPE * sc;
        float nm = fmaxf(m, sc);
        s = s * __expf(m - nm) + __expf(sc - nm);
        m = nm;
    }
    #pragma unroll
    for (int off = 4; off > 0; off >>= 1) {
        float om = __shfl_xor(m, off);
        float os = __shfl_xor(s, off);
        float nm = fmaxf(m, om);
        float a = (m  == -INFINITY) ? 0.f : s  * __expf(m  - nm);
        float b = (om == -INFINITY) ? 0.f : os * __expf(om - nm);
        m = nm; s = a + b;
    }

    // phase 2: 4 channels (ushort4 = 8B) per lane, 4 edges in flight
    float4 acc = make_float4(0.f, 0.f, 0.f, 0.f);
    const ushort* hc = h + lane * 4;
    int e = beg;
    for (; e + 3 < end; e += 4) {
        int s0 = csr_src[e], s1 = csr_src[e + 1], s2 = csr_src[e + 2], s3 = csr_src[e + 3];
        float x0 = ssrc[(size_t)s0 * HEADS + hg] + sdst_n;
        float x1 = ssrc[(size_t)s1 * HEADS + hg] + sdst_n;
        float x2 = ssrc[(size_t)s2 * HEADS + hg] + sdst_n;
        float x3 = ssrc[(size_t)s3 * HEADS + hg] + sdst_n;
        ushort4 v0 = *(const ushort4*)(hc + (size_t)s0 * HC);
        ushort4 v1 = *(const ushort4*)(hc + (size_t)s1 * HC);
        ushort4 v2 = *(const ushort4*)(hc + (size_t)s2 * HC);
        ushort4 v3 = *(const ushort4*)(hc + (size_t)s3 * HC);
        x0 = x0 > 0.f ? x0 : NEG_SLOPE * x0;
        x1 = x1 > 0.f ? x1 : NEG_SLOPE * x1;
        x2 = x2 > 0.f ? x2 : NEG_SLOPE * x2;
        x3 = x3 > 0.f ? x3 : NEG_SLOPE * x3;
        float w0 = __expf(x0 - m), w1 = __expf(x1 - m);
        float w2 = __expf(x2 - m), w3 = __expf(x3 - m);
        acc.x += w0 * bf2f(v0.x) + w1 * bf2f(v1.x) + w2 * bf2f(v2.x) + w3 * bf2f(v3.x);
        acc.y += w0 * bf2f(v0.y) + w1 * bf2f(v1.y) + w2 * bf2f(v2.y) + w3 * bf2f(v3.y);
        acc.z += w0 * bf2f(v0.z) + w1 * bf2f(v1.z) + w2 * bf2f(v2.z) + w3 * bf2f(v3.z);
        acc.w += w0 * bf2f(v0.w) + w1 * bf2f(v1.w) + w2 * bf2f(v2.w) + w3 * bf2f(v3.w);
    }
    for (; e < end; ++e) {
        int s0 = csr_src[e];
        float x0 = ssrc[(size_t)s0 * HEADS + hg] + sdst_n;
        x0 = x0 > 0.f ? x0 : NEG_SLOPE * x0;
        float w0 = __expf(x0 - m);
        ushort4 v0 = *(const ushort4*)(hc + (size_t)s0 * HC);
        acc.x += w0 * bf2f(v0.x); acc.y += w0 * bf2f(v0.y);
        acc.z += w0 * bf2f(v0.z); acc.w += w0 * bf2f(v0.w);
    }
    float inv = 1.f / (s + 1e-16f);
    float4 bv = *(const float4*)(bias + lane * 4);
    float4 o;
    o.x = acc.x * inv + bv.x; o.y = acc.y * inv + bv.y;
    o.z = acc.z * inv + bv.z; o.w = acc.w * inv + bv.w;
    o.x = o.x > 0.f ? o.x : expm1f(o.x);
    o.y = o.y > 0.f ? o.y : expm1f(o.y);
    o.z = o.z > 0.f ? o.z : expm1f(o.z);
    o.w = o.w > 0.f ? o.w : expm1f(o.w);
    *(float4*)(out + (size_t)n * HC + lane * 4) = o;
}

// ---------------------------------------------------------------- layer-2 aggregation (bf16 gather)
__global__ void __launch_bounds__(64) agg2_kernel(const ushort* __restrict__ h2,
        const float* __restrict__ ssrc, const float* __restrict__ sdst,
        const int* __restrict__ rowstart, const int* __restrict__ csr_src,
        const float* __restrict__ bias, float* __restrict__ out) {
    const int n = blockIdx.x;
    const int beg = rowstart[n], end = rowstart[n + 1];
    const int t = threadIdx.x;
    const float sdst_n = sdst[n];

    float m = -INFINITY, s = 0.f;
    for (int e = beg + t; e < end; e += 64) {
        float sc = ssrc[csr_src[e]] + sdst_n;
        sc = sc > 0.f ? sc : NEG_SLOPE * sc;
        float nm = fmaxf(m, sc);
        s = s * __expf(m - nm) + __expf(sc - nm);
        m = nm;
    }
    #pragma unroll
    for (int off = 32; off > 0; off >>= 1) {
        float om = __shfl_xor(m, off);
        float os = __shfl_xor(s, off);
        float nm = fmaxf(m, om);
        float a = (m  == -INFINITY) ? 0.f : s  * __expf(m  - nm);
        float b = (om == -INFINITY) ? 0.f : os * __expf(om - nm);
        m = nm; s = a + b;
    }
    const int c = t & 31, half = t >> 5;
    float acc = 0.f;
    for (int e = beg + half; e < end; e += 2) {
        int src = csr_src[e];
        float sc = ssrc[src] + sdst_n;
        sc = sc > 0.f ? sc : NEG_SLOPE * sc;
        acc += __expf(sc - m) * bf2f(h2[(size_t)src * NCLASS + c]);
    }
    acc += __shfl_down(acc, 32);
    if (t < 32) out[(size_t)n * NCLASS + c] = acc / (s + 1e-16f) + bias[c] + 1e-6f;
}

// ---------------------------------------------------------------- launcher
extern "C" void kernel_launch(void* const* d_in, const int* in_sizes, int n_in,
                              void* d_out, int out_size, void* d_ws, size_t ws_size,
                              hipStream_t stream) {
    float*       x        = (float*)      d_in[0];   // repacked in place (restored each call)
    const int*   ei       = (const int*)  d_in[1];
    const float* W1       = (const float*)d_in[2];
    const float* att_src1 = (const float*)d_in[3];
    const float* att_dst1 = (const float*)d_in[4];
    const float* b1       = (const float*)d_in[5];
    const float* W2       = (const float*)d_in[6];
    const float* att_src2 = (const float*)d_in[7];
    const float* att_dst2 = (const float*)d_in[8];
    const float* b2       = (const float*)d_in[9];
    float* out = (float*)d_out;

    // workspace layout
    ushort* w1t_hi = (ushort*)d_ws;                        // 256*512
    ushort* w1t_lo = w1t_hi + 256 * 512;                   // 256*512
    ushort* h1b   = w1t_lo + 256 * 512;                    // N*HC bf16
    ushort* h2b   = h1b + (size_t)N_NODES * HC;            // N*NCLASS bf16
    float* out1  = (float*)(h2b + (size_t)N_NODES * NCLASS);   // N*HC fp32
    float* ssrc1 = out1 + (size_t)N_NODES * HC;            // N*HEADS
    float* sdst1 = ssrc1 + (size_t)N_NODES * HEADS;        // N*HEADS
    float* ssrc2 = sdst1 + (size_t)N_NODES * HEADS;        // N
    float* sdst2 = ssrc2 + N_NODES;                        // N
    int* rowstart = (int*)(sdst2 + N_NODES);               // N+1
    int* deg      = rowstart + N_NODES + 1;                // N
    int* cursor   = deg + N_NODES;                         // N
    int* csr_src  = cursor + N_NODES;                      // E2
    int* blocksum = csr_src + E2;                          // SCAN_NB
    int* blockoff = blocksum + SCAN_NB;                    // SCAN_NB

    // CSR build
    hipMemsetAsync(deg, 0, N_NODES * sizeof(int), stream);
    hipMemsetAsync(cursor, 0, N_NODES * sizeof(int), stream);
    int eb = (E2 + 255) / 256;
    count_deg<<<eb, 256, 0, stream>>>(ei, deg);
    scan1_kernel<<<SCAN_NB, SCAN_B, 0, stream>>>(deg, rowstart, blocksum);
    scan2_kernel<<<1, 256, 0, stream>>>(blocksum, blockoff, rowstart);
    scan3_kernel<<<SCAN_NB, SCAN_B, 0, stream>>>(rowstart, blockoff);
    fill_csr<<<eb, 256, 0, stream>>>(ei, rowstart, cursor, csr_src);

    // precision split
    split_x_kernel<<<(N_NODES * F_IN / 4) / 256, 256, 0, stream>>>(x);
    split_w1t_kernel<<<(256 * 512) / 256, 256, 0, stream>>>(W1, w1t_hi, w1t_lo);

    // layer 1: MFMA GEMM -> bf16 h1
    {
        dim3 grid((N_NODES + 127) / 128, HC / 128);
        gemm1_mfma_kernel<<<grid, 256, 0, stream>>>((const uint*)x, w1t_hi, w1t_lo, h1b, N_NODES);
    }
    scores1_kernel<<<(N_NODES * HEADS + 255) / 256, 256, 0, stream>>>(h1b, att_src1, att_dst1, ssrc1, sdst1);
    agg1_wave_kernel<<<(N_NODES + 3) / 4, 256, 0, stream>>>(h1b, ssrc1, sdst1, rowstart, csr_src, b1, out1);

    // layer 2: fp32 GEMM -> bf16 h2
    {
        dim3 grid((N_NODES + 63) / 64, NCLASS / 32);
        gemm_bf16out_kernel<64, 32, 16, 4, 2, HC, NCLASS><<<grid, 256, 0, stream>>>(out1, W2, h2b, N_NODES);
    }
    scores2_kernel<<<(N_NODES + 255) / 256, 256, 0, stream>>>(h2b, att_src2, att_dst2, ssrc2, sdst2);
    agg2_kernel<<<N_NODES, 64, 0, stream>>>(h2b, ssrc2, sdst2, rowstart, csr_src, b2, out);
}

// Round 5
// 447.056 us; speedup vs baseline: 1.7593x; 1.1156x over previous
//
#include <hip/hip_runtime.h>
#include <math.h>

#define N_NODES 50000
#define N_EDGES 800000
#define E2 (N_EDGES + N_NODES)   // with self loops
#define F_IN 512
#define HEADS 8
#define HID 32
#define HC 256                    // HEADS*HID
#define NCLASS 32
#define NEG_SLOPE 0.2f

typedef unsigned int uint;
typedef unsigned short ushort;
typedef __attribute__((ext_vector_type(8))) short bf16x8;   // 8 bf16 (4 VGPRs)
typedef __attribute__((ext_vector_type(4))) float f32x4;

#define GLOBAL_LOAD_LDS16(g, l) \
    __builtin_amdgcn_global_load_lds((const __attribute__((address_space(1))) void*)(g), \
                                     (__attribute__((address_space(3))) void*)(l), 16, 0, 0)

__device__ inline uint bf16_rne_bits(float f) {
    uint u = __float_as_uint(f);
    return (u + 0x7fffu + ((u >> 16) & 1u)) >> 16;
}
__device__ inline float bf2f(ushort u) { return __uint_as_float(((uint)u) << 16); }

// ------------------------------------------------ W1 [512][256] -> W1^T hi/lo bf16 [256][512]
__global__ void split_w1t_kernel(const float* __restrict__ W1,
                                 ushort* __restrict__ hi, ushort* __restrict__ lo) {
    int t = blockIdx.x * 256 + threadIdx.x;      // t = n*512 + k, t < 131072
    int n = t >> 9, k = t & 511;
    float f = W1[k * 256 + n];
    uint h = bf16_rne_bits(f);
    float r = f - __uint_as_float(h << 16);
    hi[t] = (ushort)h;
    lo[t] = (ushort)bf16_rne_bits(r);
}

// ------------------------------------------------ MFMA GEMM1: h1b[M,256] = x @ W1 (split bf16, 3-term)
// xp: [M][512] RAW fp32 bits; split hi/lo on the fly (trunc hi + trunc residual).
// bhi/blo: [256][512] bf16 (W1^T); output bf16
__global__ void __launch_bounds__(256) gemm1_mfma_kernel(const uint* __restrict__ xp,
        const ushort* __restrict__ bhi, const ushort* __restrict__ blo,
        ushort* __restrict__ C, int M) {
    __shared__ uint   As[128 * 32];   // 16 KB fp32 bits, chunk-swizzled: phys chunk = row*8 + (c ^ (row&7))
    __shared__ ushort Bh[128 * 32];   // 8 KB,  phys chunk = row*4 + (q ^ ((row>>1)&3))
    __shared__ ushort Bl[128 * 32];   // 8 KB
    const int tid = threadIdx.x, lane = tid & 63, wave = tid >> 6;
    const int bm = blockIdx.x * 128, bn = blockIdx.y * 128;

    const uint* agp[4]; const uint* alp[4];
    #pragma unroll
    for (int s = 0; s < 4; ++s) {
        int t = wave * 4 + s;
        int p = t * 64 + lane;           // physical chunk 0..1023
        int row = p >> 3, cs = p & 7;
        int c = cs ^ (row & 7);          // global k-chunk (4 u32 each)
        int grow = bm + row; if (grow > M - 1) grow = M - 1;
        agp[s] = xp + ((size_t)grow * 512 + c * 4);
        alp[s] = &As[t * 256];           // wave-uniform LDS base; HW adds lane*16B
    }
    const ushort* bhgp[2]; const ushort* blgp[2]; const ushort* bhlp[2]; const ushort* bllp[2];
    #pragma unroll
    for (int s = 0; s < 2; ++s) {
        int t = wave * 2 + s;
        int p = t * 64 + lane;           // physical chunk 0..511
        int row = p >> 2, qs = p & 3;
        int q = qs ^ ((row >> 1) & 3);   // global k-chunk (8 bf16 each)
        size_t go = (size_t)(bn + row) * 512 + q * 8;
        bhgp[s] = bhi + go; blgp[s] = blo + go;
        bhlp[s] = &Bh[t * 512]; bllp[s] = &Bl[t * 512];
    }

    f32x4 acc[4][4] = {};
    const int wm = (wave >> 1) * 64, wn = (wave & 1) * 64;
    const int fm = lane & 15, quad = lane >> 4;

    for (int kk = 0; kk < 16; ++kk) {
        #pragma unroll
        for (int s = 0; s < 4; ++s) GLOBAL_LOAD_LDS16(agp[s], alp[s]);
        #pragma unroll
        for (int s = 0; s < 2; ++s) {
            GLOBAL_LOAD_LDS16(bhgp[s], bhlp[s]);
            GLOBAL_LOAD_LDS16(blgp[s], bllp[s]);
        }
        #pragma unroll
        for (int s = 0; s < 4; ++s) agp[s] += 32;
        #pragma unroll
        for (int s = 0; s < 2; ++s) { bhgp[s] += 32; blgp[s] += 32; }
        __syncthreads();

        bf16x8 ah[4], al[4], bh[4], bl[4];
        #pragma unroll
        for (int i = 0; i < 4; ++i) {
            int row = wm + i * 16 + fm;
            int sw = row & 7;
            uint4 c0 = *(const uint4*)&As[row * 32 + (((2 * quad)     ^ sw) * 4)];
            uint4 c1 = *(const uint4*)&As[row * 32 + (((2 * quad + 1) ^ sw) * 4)];
            union { uint u[4]; bf16x8 v; } H, L;
            // hi = truncated top-16 bits of fp32 (residual captures trunc error)
            H.u[0] = __builtin_amdgcn_perm(c0.y, c0.x, 0x07060302u);
            H.u[1] = __builtin_amdgcn_perm(c0.w, c0.z, 0x07060302u);
            H.u[2] = __builtin_amdgcn_perm(c1.y, c1.x, 0x07060302u);
            H.u[3] = __builtin_amdgcn_perm(c1.w, c1.z, 0x07060302u);
            // residual = f - hi, truncated to bf16
            uint r0 = __float_as_uint(__uint_as_float(c0.x) - __uint_as_float(c0.x & 0xffff0000u));
            uint r1 = __float_as_uint(__uint_as_float(c0.y) - __uint_as_float(c0.y & 0xffff0000u));
            uint r2 = __float_as_uint(__uint_as_float(c0.z) - __uint_as_float(c0.z & 0xffff0000u));
            uint r3 = __float_as_uint(__uint_as_float(c0.w) - __uint_as_float(c0.w & 0xffff0000u));
            uint r4 = __float_as_uint(__uint_as_float(c1.x) - __uint_as_float(c1.x & 0xffff0000u));
            uint r5 = __float_as_uint(__uint_as_float(c1.y) - __uint_as_float(c1.y & 0xffff0000u));
            uint r6 = __float_as_uint(__uint_as_float(c1.z) - __uint_as_float(c1.z & 0xffff0000u));
            uint r7 = __float_as_uint(__uint_as_float(c1.w) - __uint_as_float(c1.w & 0xffff0000u));
            L.u[0] = __builtin_amdgcn_perm(r1, r0, 0x07060302u);
            L.u[1] = __builtin_amdgcn_perm(r3, r2, 0x07060302u);
            L.u[2] = __builtin_amdgcn_perm(r5, r4, 0x07060302u);
            L.u[3] = __builtin_amdgcn_perm(r7, r6, 0x07060302u);
            ah[i] = H.v; al[i] = L.v;
        }
        #pragma unroll
        for (int j = 0; j < 4; ++j) {
            int row = wn + j * 16 + fm;
            int qs = quad ^ ((row >> 1) & 3);
            bh[j] = *(const bf16x8*)&Bh[row * 32 + qs * 8];
            bl[j] = *(const bf16x8*)&Bl[row * 32 + qs * 8];
        }
        #pragma unroll
        for (int i = 0; i < 4; ++i)
            #pragma unroll
            for (int j = 0; j < 4; ++j) {
                acc[i][j] = __builtin_amdgcn_mfma_f32_16x16x32_bf16(ah[i], bh[j], acc[i][j], 0, 0, 0);
                acc[i][j] = __builtin_amdgcn_mfma_f32_16x16x32_bf16(ah[i], bl[j], acc[i][j], 0, 0, 0);
                acc[i][j] = __builtin_amdgcn_mfma_f32_16x16x32_bf16(al[i], bh[j], acc[i][j], 0, 0, 0);
            }
        __syncthreads();
    }

    // epilogue: C/D layout col=lane&15, row=quad*4+reg (m89-verified); write bf16
    #pragma unroll
    for (int i = 0; i < 4; ++i) {
        int rb = bm + wm + i * 16 + quad * 4;
        #pragma unroll
        for (int j = 0; j < 4; ++j) {
            int col = bn + wn + j * 16 + fm;
            #pragma unroll
            for (int r = 0; r < 4; ++r) {
                int row = rb + r;
                if (row < M) C[(size_t)row * 256 + col] = (ushort)bf16_rne_bits(acc[i][j][r]);
            }
        }
    }
}

// ---------------------------------------------------------------- CSR build
__global__ void count_deg(const int* __restrict__ ei, int* __restrict__ deg) {
    int e = blockIdx.x * blockDim.x + threadIdx.x;
    if (e >= E2) return;
    int dst = (e < N_EDGES) ? ei[N_EDGES + e] : (e - N_EDGES);
    atomicAdd(&deg[dst], 1);
}

#define SCAN_B 256
#define SCAN_NB ((N_NODES + SCAN_B - 1) / SCAN_B)   // 196

// rowstart[i] (i<=N) = block-local exclusive prefix; final = rowstart[i] + blockoff[i>>8]
__global__ void scan1_kernel(const int* __restrict__ deg, int* __restrict__ rowstart,
                             int* __restrict__ blocksum) {
    __shared__ int sm[SCAN_B];
    int t = threadIdx.x, i = blockIdx.x * SCAN_B + t;
    int v = (i < N_NODES) ? deg[i] : 0;
    sm[t] = v; __syncthreads();
    int x = v;
    for (int off = 1; off < SCAN_B; off <<= 1) {
        int y = (t >= off) ? sm[t - off] : 0; __syncthreads();
        x += y; sm[t] = x; __syncthreads();
    }
    if (i <= N_NODES) rowstart[i] = x - v;           // includes boundary elem i==N
    if (t == SCAN_B - 1) blocksum[blockIdx.x] = x;
}

__global__ void scan2_kernel(const int* __restrict__ blocksum, int* __restrict__ blockoff) {
    __shared__ int sm[256];
    int t = threadIdx.x;
    int v = (t < SCAN_NB) ? blocksum[t] : 0;
    sm[t] = v; __syncthreads();
    int x = v;
    for (int off = 1; off < 256; off <<= 1) {
        int y = (t >= off) ? sm[t - off] : 0; __syncthreads();
        x += y; sm[t] = x; __syncthreads();
    }
    if (t < SCAN_NB) blockoff[t] = x - v;            // exclusive block offsets
}

__global__ void fill_csr(const int* __restrict__ ei, const int* __restrict__ rowstart,
                         const int* __restrict__ blockoff,
                         int* __restrict__ cursor, int* __restrict__ csr_src) {
    int e = blockIdx.x * blockDim.x + threadIdx.x;
    if (e >= E2) return;
    int src, dst;
    if (e < N_EDGES) { src = ei[e]; dst = ei[N_EDGES + e]; }
    else             { src = e - N_EDGES; dst = src; }
    int p = atomicAdd(&cursor[dst], 1);
    csr_src[rowstart[dst] + blockoff[dst >> 8] + p] = src;
}

// ---------------------------------------------------------------- fp32 GEMM small-N (layer 2), bf16 out
template<int BM, int BN, int BK, int TM, int TN, int K, int NOUT>
__global__ void __launch_bounds__(256) gemm_bf16out_kernel(const float* __restrict__ A,
                                                           const float* __restrict__ B,
                                                           ushort* __restrict__ C, int M) {
    __shared__ float As[BK][BM];
    __shared__ float Bs[BK][BN];
    const int tid = threadIdx.x;
    const int bm = blockIdx.x * BM;
    const int bn = blockIdx.y * BN;
    constexpr int TX = BN / TN;
    const int tx = tid % TX;
    const int ty = tid / TX;
    float acc[TM][TN] = {};
    constexpr int A4 = BM * BK / 4;
    constexpr int AR = BK / 4;
    constexpr int B4 = BK * BN / 4;
    constexpr int BR = BN / 4;

    for (int k0 = 0; k0 < K; k0 += BK) {
        for (int i = tid; i < A4; i += 256) {
            int row = i / AR;
            int kc  = (i % AR) * 4;
            float4 v = make_float4(0.f, 0.f, 0.f, 0.f);
            int grow = bm + row;
            if (grow < M) v = *(const float4*)(A + (size_t)grow * K + k0 + kc);
            As[kc + 0][row] = v.x; As[kc + 1][row] = v.y;
            As[kc + 2][row] = v.z; As[kc + 3][row] = v.w;
        }
        for (int i = tid; i < B4; i += 256) {
            int row = i / BR;
            int nc  = (i % BR) * 4;
            *(float4*)&Bs[row][nc] = *(const float4*)(B + (size_t)(k0 + row) * NOUT + bn + nc);
        }
        __syncthreads();
        #pragma unroll
        for (int k = 0; k < BK; ++k) {
            float af[TM], bf[TN];
            #pragma unroll
            for (int i = 0; i < TM; ++i) af[i] = As[k][ty * TM + i];
            #pragma unroll
            for (int j = 0; j < TN; ++j) bf[j] = Bs[k][tx * TN + j];
            #pragma unroll
            for (int i = 0; i < TM; ++i)
                #pragma unroll
                for (int j = 0; j < TN; ++j)
                    acc[i][j] += af[i] * bf[j];
        }
        __syncthreads();
    }
    #pragma unroll
    for (int i = 0; i < TM; ++i) {
        int grow = bm + ty * TM + i;
        if (grow >= M) continue;
        ushort* cp = C + (size_t)grow * NOUT + bn + tx * TN;
        static_assert(TN == 2, "bf16 out pack assumes TN==2");
        uint pk = bf16_rne_bits(acc[i][0]) | (bf16_rne_bits(acc[i][1]) << 16);
        *(uint*)cp = pk;
    }
}

// ---------------------------------------------------------------- scores (bf16 inputs)
__global__ void scores1_kernel(const ushort* __restrict__ h, const float* __restrict__ asrc,
                               const float* __restrict__ adst,
                               float* __restrict__ ssrc, float* __restrict__ sdst) {
    int gid = blockIdx.x * blockDim.x + threadIdx.x;
    int n = gid >> 3, hh = gid & 7;
    if (n >= N_NODES) return;
    const uint* hp = (const uint*)(h + (size_t)n * HC + hh * HID);  // 16 uints = 32 bf16
    const float* as = asrc + hh * HID;
    const float* ad = adst + hh * HID;
    float s1 = 0.f, s2 = 0.f;
    #pragma unroll
    for (int q = 0; q < 4; ++q) {
        uint4 u = ((const uint4*)hp)[q];
        uint w[4] = {u.x, u.y, u.z, u.w};
        #pragma unroll
        for (int k = 0; k < 4; ++k) {
            int c = q * 8 + k * 2;
            float v0 = __uint_as_float(w[k] << 16);
            float v1 = __uint_as_float(w[k] & 0xffff0000u);
            s1 += v0 * as[c] + v1 * as[c + 1];
            s2 += v0 * ad[c] + v1 * ad[c + 1];
        }
    }
    ssrc[n * HEADS + hh] = s1;
    sdst[n * HEADS + hh] = s2;
}

__global__ void scores2_kernel(const ushort* __restrict__ h2, const float* __restrict__ asrc,
                               const float* __restrict__ adst,
                               float* __restrict__ ssrc, float* __restrict__ sdst) {
    int n = blockIdx.x * blockDim.x + threadIdx.x;
    if (n >= N_NODES) return;
    const uint* hp = (const uint*)(h2 + (size_t)n * NCLASS);
    float s1 = 0.f, s2 = 0.f;
    #pragma unroll
    for (int q = 0; q < 4; ++q) {
        uint4 u = ((const uint4*)hp)[q];
        uint w[4] = {u.x, u.y, u.z, u.w};
        #pragma unroll
        for (int k = 0; k < 4; ++k) {
            int c = q * 8 + k * 2;
            float v0 = __uint_as_float(w[k] << 16);
            float v1 = __uint_as_float(w[k] & 0xffff0000u);
            s1 += v0 * asrc[c] + v1 * asrc[c + 1];
            s2 += v0 * adst[c] + v1 * adst[c + 1];
        }
    }
    ssrc[n] = s1; sdst[n] = s2;
}

// ---------------------------------------------------------------- layer-1 aggregation (bf16 gather)
__global__ void __launch_bounds__(256) agg1_wave_kernel(const ushort* __restrict__ h,
        const float* __restrict__ ssrc, const float* __restrict__ sdst,
        const int* __restrict__ rowstart, const int* __restrict__ blockoff,
        const int* __restrict__ csr_src,
        const float* __restrict__ bias, float* __restrict__ out) {
    const int wid = (blockIdx.x * blockDim.x + threadIdx.x) >> 6;   // node id
    if (wid >= N_NODES) return;
    const int lane = threadIdx.x & 63;
    const int hg = lane >> 3;
    const int hl = lane & 7;
    const int n = wid;
    const int beg = rowstart[n] + blockoff[n >> 8];
    const int end = rowstart[n + 1] + blockoff[(n + 1) >> 8];
    const float sdst_n = sdst[(size_t)n * HEADS + hg];

    // phase 1: per-head online softmax, 8 lanes per head
    float m = -INFINITY, s = 0.f;
    for (int e = beg + hl; e < end; e += 8) {
        int src = csr_src[e];
        float sc = ssrc[(size_t)src * HEADS + hg] + sdst_n;
        sc = sc > 0.f ? sc : NEG_SLOPE * sc;
        float nm = fmaxf(m, sc);
        s = s * __expf(m - nm) + __expf(sc - nm);
        m = nm;
    }
    #pragma unroll
    for (int off = 4; off > 0; off >>= 1) {
        float om = __shfl_xor(m, off);
        float os = __shfl_xor(s, off);
        float nm = fmaxf(m, om);
        float a = (m  == -INFINITY) ? 0.f : s  * __expf(m  - nm);
        float b = (om == -INFINITY) ? 0.f : os * __expf(om - nm);
        m = nm; s = a + b;
    }

    // phase 2: 4 channels (ushort4 = 8B) per lane, 4 edges in flight
    float4 acc = make_float4(0.f, 0.f, 0.f, 0.f);
    const ushort* hc = h + lane * 4;
    int e = beg;
    for (; e + 3 < end; e += 4) {
        int s0 = csr_src[e], s1 = csr_src[e + 1], s2 = csr_src[e + 2], s3 = csr_src[e + 3];
        float x0 = ssrc[(size_t)s0 * HEADS + hg] + sdst_n;
        float x1 = ssrc[(size_t)s1 * HEADS + hg] + sdst_n;
        float x2 = ssrc[(size_t)s2 * HEADS + hg] + sdst_n;
        float x3 = ssrc[(size_t)s3 * HEADS + hg] + sdst_n;
        ushort4 v0 = *(const ushort4*)(hc + (size_t)s0 * HC);
        ushort4 v1 = *(const ushort4*)(hc + (size_t)s1 * HC);
        ushort4 v2 = *(const ushort4*)(hc + (size_t)s2 * HC);
        ushort4 v3 = *(const ushort4*)(hc + (size_t)s3 * HC);
        x0 = x0 > 0.f ? x0 : NEG_SLOPE * x0;
        x1 = x1 > 0.f ? x1 : NEG_SLOPE * x1;
        x2 = x2 > 0.f ? x2 : NEG_SLOPE * x2;
        x3 = x3 > 0.f ? x3 : NEG_SLOPE * x3;
        float w0 = __expf(x0 - m), w1 = __expf(x1 - m);
        float w2 = __expf(x2 - m), w3 = __expf(x3 - m);
        acc.x += w0 * bf2f(v0.x) + w1 * bf2f(v1.x) + w2 * bf2f(v2.x) + w3 * bf2f(v3.x);
        acc.y += w0 * bf2f(v0.y) + w1 * bf2f(v1.y) + w2 * bf2f(v2.y) + w3 * bf2f(v3.y);
        acc.z += w0 * bf2f(v0.z) + w1 * bf2f(v1.z) + w2 * bf2f(v2.z) + w3 * bf2f(v3.z);
        acc.w += w0 * bf2f(v0.w) + w1 * bf2f(v1.w) + w2 * bf2f(v2.w) + w3 * bf2f(v3.w);
    }
    for (; e < end; ++e) {
        int s0 = csr_src[e];
        float x0 = ssrc[(size_t)s0 * HEADS + hg] + sdst_n;
        x0 = x0 > 0.f ? x0 : NEG_SLOPE * x0;
        float w0 = __expf(x0 - m);
        ushort4 v0 = *(const ushort4*)(hc + (size_t)s0 * HC);
        acc.x += w0 * bf2f(v0.x); acc.y += w0 * bf2f(v0.y);
        acc.z += w0 * bf2f(v0.z); acc.w += w0 * bf2f(v0.w);
    }
    float inv = 1.f / (s + 1e-16f);
    float4 bv = *(const float4*)(bias + lane * 4);
    float4 o;
    o.x = acc.x * inv + bv.x; o.y = acc.y * inv + bv.y;
    o.z = acc.z * inv + bv.z; o.w = acc.w * inv + bv.w;
    o.x = o.x > 0.f ? o.x : expm1f(o.x);
    o.y = o.y > 0.f ? o.y : expm1f(o.y);
    o.z = o.z > 0.f ? o.z : expm1f(o.z);
    o.w = o.w > 0.f ? o.w : expm1f(o.w);
    *(float4*)(out + (size_t)n * HC + lane * 4) = o;
}

// ---------------------------------------------------------------- layer-2 aggregation (bf16 gather)
// one wave per node; phase 2: slot=t>>4 (4 edges in flight), ch pair = t&15
__global__ void __launch_bounds__(64) agg2_kernel(const ushort* __restrict__ h2,
        const float* __restrict__ ssrc, const float* __restrict__ sdst,
        const int* __restrict__ rowstart, const int* __restrict__ blockoff,
        const int* __restrict__ csr_src,
        const float* __restrict__ bias, float* __restrict__ out) {
    const int n = blockIdx.x;
    const int beg = rowstart[n] + blockoff[n >> 8];
    const int end = rowstart[n + 1] + blockoff[(n + 1) >> 8];
    const int t = threadIdx.x;
    const float sdst_n = sdst[n];

    float m = -INFINITY, s = 0.f;
    for (int e = beg + t; e < end; e += 64) {
        float sc = ssrc[csr_src[e]] + sdst_n;
        sc = sc > 0.f ? sc : NEG_SLOPE * sc;
        float nm = fmaxf(m, sc);
        s = s * __expf(m - nm) + __expf(sc - nm);
        m = nm;
    }
    #pragma unroll
    for (int off = 32; off > 0; off >>= 1) {
        float om = __shfl_xor(m, off);
        float os = __shfl_xor(s, off);
        float nm = fmaxf(m, om);
        float a = (m  == -INFINITY) ? 0.f : s  * __expf(m  - nm);
        float b = (om == -INFINITY) ? 0.f : os * __expf(om - nm);
        m = nm; s = a + b;
    }
    const int slot = t >> 4, cp = t & 15;   // channels 2cp, 2cp+1
    float a0 = 0.f, a1 = 0.f;
    for (int e = beg + slot; e < end; e += 4) {
        int src = csr_src[e];
        float sc = ssrc[src] + sdst_n;
        sc = sc > 0.f ? sc : NEG_SLOPE * sc;
        float w = __expf(sc - m);
        uint v = *(const uint*)(h2 + (size_t)src * NCLASS + cp * 2);
        a0 += w * __uint_as_float(v << 16);
        a1 += w * __uint_as_float(v & 0xffff0000u);
    }
    a0 += __shfl_down(a0, 32); a1 += __shfl_down(a1, 32);
    a0 += __shfl_down(a0, 16); a1 += __shfl_down(a1, 16);
    if (t < 16) {
        float inv = 1.f / (s + 1e-16f);
        float2 o;
        o.x = a0 * inv + bias[cp * 2]     + 1e-6f;
        o.y = a1 * inv + bias[cp * 2 + 1] + 1e-6f;
        *(float2*)(out + (size_t)n * NCLASS + cp * 2) = o;
    }
}

// ---------------------------------------------------------------- launcher
extern "C" void kernel_launch(void* const* d_in, const int* in_sizes, int n_in,
                              void* d_out, int out_size, void* d_ws, size_t ws_size,
                              hipStream_t stream) {
    const float* x        = (const float*)d_in[0];
    const int*   ei       = (const int*)  d_in[1];
    const float* W1       = (const float*)d_in[2];
    const float* att_src1 = (const float*)d_in[3];
    const float* att_dst1 = (const float*)d_in[4];
    const float* b1       = (const float*)d_in[5];
    const float* W2       = (const float*)d_in[6];
    const float* att_src2 = (const float*)d_in[7];
    const float* att_dst2 = (const float*)d_in[8];
    const float* b2       = (const float*)d_in[9];
    float* out = (float*)d_out;

    // workspace layout
    ushort* w1t_hi = (ushort*)d_ws;                        // 256*512
    ushort* w1t_lo = w1t_hi + 256 * 512;                   // 256*512
    ushort* h1b   = w1t_lo + 256 * 512;                    // N*HC bf16
    ushort* h2b   = h1b + (size_t)N_NODES * HC;            // N*NCLASS bf16
    float* out1  = (float*)(h2b + (size_t)N_NODES * NCLASS);   // N*HC fp32
    float* ssrc1 = out1 + (size_t)N_NODES * HC;            // N*HEADS
    float* sdst1 = ssrc1 + (size_t)N_NODES * HEADS;        // N*HEADS
    float* ssrc2 = sdst1 + (size_t)N_NODES * HEADS;        // N
    float* sdst2 = ssrc2 + N_NODES;                        // N
    int* rowstart = (int*)(sdst2 + N_NODES);               // N+1
    int* deg      = rowstart + N_NODES + 1;                // N   (deg+cursor zeroed together)
    int* cursor   = deg + N_NODES;                         // N
    int* csr_src  = cursor + N_NODES;                      // E2
    int* blocksum = csr_src + E2;                          // SCAN_NB
    int* blockoff = blocksum + SCAN_NB;                    // SCAN_NB

    // CSR build (rowstart kept block-local; consumers add blockoff[i>>8])
    hipMemsetAsync(deg, 0, 2 * N_NODES * sizeof(int), stream);   // deg + cursor
    int eb = (E2 + 255) / 256;
    count_deg<<<eb, 256, 0, stream>>>(ei, deg);
    scan1_kernel<<<SCAN_NB, SCAN_B, 0, stream>>>(deg, rowstart, blocksum);
    scan2_kernel<<<1, 256, 0, stream>>>(blocksum, blockoff);
    fill_csr<<<eb, 256, 0, stream>>>(ei, rowstart, blockoff, cursor, csr_src);

    // W1 split (x is consumed raw by gemm1 — no split_x pass)
    split_w1t_kernel<<<(256 * 512) / 256, 256, 0, stream>>>(W1, w1t_hi, w1t_lo);

    // layer 1: MFMA GEMM -> bf16 h1
    {
        dim3 grid((N_NODES + 127) / 128, HC / 128);
        gemm1_mfma_kernel<<<grid, 256, 0, stream>>>((const uint*)x, w1t_hi, w1t_lo, h1b, N_NODES);
    }
    scores1_kernel<<<(N_NODES * HEADS + 255) / 256, 256, 0, stream>>>(h1b, att_src1, att_dst1, ssrc1, sdst1);
    agg1_wave_kernel<<<(N_NODES + 3) / 4, 256, 0, stream>>>(h1b, ssrc1, sdst1, rowstart, blockoff, csr_src, b1, out1);

    // layer 2: fp32 GEMM -> bf16 h2
    {
        dim3 grid((N_NODES + 63) / 64, NCLASS / 32);
        gemm_bf16out_kernel<64, 32, 16, 4, 2, HC, NCLASS><<<grid, 256, 0, stream>>>(out1, W2, h2b, N_NODES);
    }
    scores2_kernel<<<(N_NODES + 255) / 256, 256, 0, stream>>>(h2b, att_src2, att_dst2, ssrc2, sdst2);
    agg2_kernel<<<N_NODES, 64, 0, stream>>>(h2b, ssrc2, sdst2, rowstart, blockoff, csr_src, b2, out);
}

// Round 6
// 444.481 us; speedup vs baseline: 1.7695x; 1.0058x over previous
//
#include <hip/hip_runtime.h>
#include <math.h>

#define N_NODES 50000
#define N_EDGES 800000
#define E2 (N_EDGES + N_NODES)   // with self loops
#define F_IN 512
#define HEADS 8
#define HID 32
#define HC 256                    // HEADS*HID
#define NCLASS 32
#define NEG_SLOPE 0.2f

typedef unsigned int uint;
typedef unsigned short ushort;
typedef __attribute__((ext_vector_type(8))) short bf16x8;   // 8 bf16 (4 VGPRs)
typedef __attribute__((ext_vector_type(4))) float f32x4;

#define GLOBAL_LOAD_LDS16(g, l) \
    __builtin_amdgcn_global_load_lds((const __attribute__((address_space(1))) void*)(g), \
                                     (__attribute__((address_space(3))) void*)(l), 16, 0, 0)

__device__ inline uint bf16_rne_bits(float f) {
    uint u = __float_as_uint(f);
    return (u + 0x7fffu + ((u >> 16) & 1u)) >> 16;
}
__device__ inline float bf2f(ushort u) { return __uint_as_float(((uint)u) << 16); }

// ------------------------------------------------ W1 [512][256] -> W1^T hi/lo bf16 [256][512]
__global__ void split_w1t_kernel(const float* __restrict__ W1,
                                 ushort* __restrict__ hi, ushort* __restrict__ lo) {
    int t = blockIdx.x * 256 + threadIdx.x;      // t = n*512 + k, t < 131072
    int n = t >> 9, k = t & 511;
    float f = W1[k * 256 + n];
    uint h = bf16_rne_bits(f);
    float r = f - __uint_as_float(h << 16);
    hi[t] = (ushort)h;
    lo[t] = (ushort)bf16_rne_bits(r);
}

// ------------------------------------------------ W2 [256][32] -> W2^T hi/lo bf16 [32][256]
__global__ void split_w2t_kernel(const float* __restrict__ W2,
                                 ushort* __restrict__ hi, ushort* __restrict__ lo) {
    int t = blockIdx.x * 256 + threadIdx.x;      // t = n*256 + k, t < 8192
    int n = t >> 8, k = t & 255;
    float f = W2[k * 32 + n];
    uint h = bf16_rne_bits(f);
    float r = f - __uint_as_float(h << 16);
    hi[t] = (ushort)h;
    lo[t] = (ushort)bf16_rne_bits(r);
}

// ------------------------------------------------ MFMA GEMM1: h1b[M,256] = x @ W1 (split bf16, 3-term)
__global__ void __launch_bounds__(256) gemm1_mfma_kernel(const uint* __restrict__ xp,
        const ushort* __restrict__ bhi, const ushort* __restrict__ blo,
        ushort* __restrict__ C, int M) {
    __shared__ uint   As[128 * 32];   // 16 KB fp32 bits, chunk-swizzled: phys chunk = row*8 + (c ^ (row&7))
    __shared__ ushort Bh[128 * 32];   // 8 KB,  phys chunk = row*4 + (q ^ ((row>>1)&3))
    __shared__ ushort Bl[128 * 32];   // 8 KB
    const int tid = threadIdx.x, lane = tid & 63, wave = tid >> 6;
    const int bm = blockIdx.x * 128, bn = blockIdx.y * 128;

    const uint* agp[4]; const uint* alp[4];
    #pragma unroll
    for (int s = 0; s < 4; ++s) {
        int t = wave * 4 + s;
        int p = t * 64 + lane;           // physical chunk 0..1023
        int row = p >> 3, cs = p & 7;
        int c = cs ^ (row & 7);          // global k-chunk (4 u32 each)
        int grow = bm + row; if (grow > M - 1) grow = M - 1;
        agp[s] = xp + ((size_t)grow * 512 + c * 4);
        alp[s] = &As[t * 256];           // wave-uniform LDS base; HW adds lane*16B
    }
    const ushort* bhgp[2]; const ushort* blgp[2]; const ushort* bhlp[2]; const ushort* bllp[2];
    #pragma unroll
    for (int s = 0; s < 2; ++s) {
        int t = wave * 2 + s;
        int p = t * 64 + lane;           // physical chunk 0..511
        int row = p >> 2, qs = p & 3;
        int q = qs ^ ((row >> 1) & 3);   // global k-chunk (8 bf16 each)
        size_t go = (size_t)(bn + row) * 512 + q * 8;
        bhgp[s] = bhi + go; blgp[s] = blo + go;
        bhlp[s] = &Bh[t * 512]; bllp[s] = &Bl[t * 512];
    }

    f32x4 acc[4][4] = {};
    const int wm = (wave >> 1) * 64, wn = (wave & 1) * 64;
    const int fm = lane & 15, quad = lane >> 4;

    for (int kk = 0; kk < 16; ++kk) {
        #pragma unroll
        for (int s = 0; s < 4; ++s) GLOBAL_LOAD_LDS16(agp[s], alp[s]);
        #pragma unroll
        for (int s = 0; s < 2; ++s) {
            GLOBAL_LOAD_LDS16(bhgp[s], bhlp[s]);
            GLOBAL_LOAD_LDS16(blgp[s], bllp[s]);
        }
        #pragma unroll
        for (int s = 0; s < 4; ++s) agp[s] += 32;
        #pragma unroll
        for (int s = 0; s < 2; ++s) { bhgp[s] += 32; blgp[s] += 32; }
        __syncthreads();

        bf16x8 ah[4], al[4], bh[4], bl[4];
        #pragma unroll
        for (int i = 0; i < 4; ++i) {
            int row = wm + i * 16 + fm;
            int sw = row & 7;
            uint4 c0 = *(const uint4*)&As[row * 32 + (((2 * quad)     ^ sw) * 4)];
            uint4 c1 = *(const uint4*)&As[row * 32 + (((2 * quad + 1) ^ sw) * 4)];
            union { uint u[4]; bf16x8 v; } H, L;
            H.u[0] = __builtin_amdgcn_perm(c0.y, c0.x, 0x07060302u);
            H.u[1] = __builtin_amdgcn_perm(c0.w, c0.z, 0x07060302u);
            H.u[2] = __builtin_amdgcn_perm(c1.y, c1.x, 0x07060302u);
            H.u[3] = __builtin_amdgcn_perm(c1.w, c1.z, 0x07060302u);
            uint r0 = __float_as_uint(__uint_as_float(c0.x) - __uint_as_float(c0.x & 0xffff0000u));
            uint r1 = __float_as_uint(__uint_as_float(c0.y) - __uint_as_float(c0.y & 0xffff0000u));
            uint r2 = __float_as_uint(__uint_as_float(c0.z) - __uint_as_float(c0.z & 0xffff0000u));
            uint r3 = __float_as_uint(__uint_as_float(c0.w) - __uint_as_float(c0.w & 0xffff0000u));
            uint r4 = __float_as_uint(__uint_as_float(c1.x) - __uint_as_float(c1.x & 0xffff0000u));
            uint r5 = __float_as_uint(__uint_as_float(c1.y) - __uint_as_float(c1.y & 0xffff0000u));
            uint r6 = __float_as_uint(__uint_as_float(c1.z) - __uint_as_float(c1.z & 0xffff0000u));
            uint r7 = __float_as_uint(__uint_as_float(c1.w) - __uint_as_float(c1.w & 0xffff0000u));
            L.u[0] = __builtin_amdgcn_perm(r1, r0, 0x07060302u);
            L.u[1] = __builtin_amdgcn_perm(r3, r2, 0x07060302u);
            L.u[2] = __builtin_amdgcn_perm(r5, r4, 0x07060302u);
            L.u[3] = __builtin_amdgcn_perm(r7, r6, 0x07060302u);
            ah[i] = H.v; al[i] = L.v;
        }
        #pragma unroll
        for (int j = 0; j < 4; ++j) {
            int row = wn + j * 16 + fm;
            int qs = quad ^ ((row >> 1) & 3);
            bh[j] = *(const bf16x8*)&Bh[row * 32 + qs * 8];
            bl[j] = *(const bf16x8*)&Bl[row * 32 + qs * 8];
        }
        #pragma unroll
        for (int i = 0; i < 4; ++i)
            #pragma unroll
            for (int j = 0; j < 4; ++j) {
                acc[i][j] = __builtin_amdgcn_mfma_f32_16x16x32_bf16(ah[i], bh[j], acc[i][j], 0, 0, 0);
                acc[i][j] = __builtin_amdgcn_mfma_f32_16x16x32_bf16(ah[i], bl[j], acc[i][j], 0, 0, 0);
                acc[i][j] = __builtin_amdgcn_mfma_f32_16x16x32_bf16(al[i], bh[j], acc[i][j], 0, 0, 0);
            }
        __syncthreads();
    }

    #pragma unroll
    for (int i = 0; i < 4; ++i) {
        int rb = bm + wm + i * 16 + quad * 4;
        #pragma unroll
        for (int j = 0; j < 4; ++j) {
            int col = bn + wn + j * 16 + fm;
            #pragma unroll
            for (int r = 0; r < 4; ++r) {
                int row = rb + r;
                if (row < M) C[(size_t)row * 256 + col] = (ushort)bf16_rne_bits(acc[i][j][r]);
            }
        }
    }
}

// ------------------------------------------------ MFMA GEMM2: h2b[M,32] = out1b @ W2 (2-term) + fused scores2
__global__ void __launch_bounds__(256) gemm2_mfma_kernel(const ushort* __restrict__ A,
        const ushort* __restrict__ bh_g, const ushort* __restrict__ bl_g,
        const float* __restrict__ as2, const float* __restrict__ ad2,
        ushort* __restrict__ C, float* __restrict__ ssrc, float* __restrict__ sdst, int M) {
    __shared__ ushort As[128 * 32];   // 8 KB, phys chunk = row*4 + (q ^ ((row>>1)&3))
    const int tid = threadIdx.x, lane = tid & 63, wave = tid >> 6;
    const int bm = blockIdx.x * 128;
    const int fm = lane & 15, quad = lane >> 4;
    const int wrow = wave * 32;

    const ushort* agp[2]; const ushort* alp[2];
    #pragma unroll
    for (int s = 0; s < 2; ++s) {
        int t = wave * 2 + s;
        int p = t * 64 + lane;           // chunk 0..511
        int row = p >> 2, qs = p & 3;
        int q = qs ^ ((row >> 1) & 3);
        int gr = bm + row; if (gr > M - 1) gr = M - 1;
        agp[s] = A + (size_t)gr * 256 + q * 8;
        alp[s] = &As[t * 512];
    }

    f32x4 acc[2][2] = {};
    for (int kk = 0; kk < 8; ++kk) {
        GLOBAL_LOAD_LDS16(agp[0], alp[0]);
        GLOBAL_LOAD_LDS16(agp[1], alp[1]);
        agp[0] += 32; agp[1] += 32;
        __syncthreads();
        bf16x8 a[2], bh[2], bl[2];
        #pragma unroll
        for (int i = 0; i < 2; ++i) {
            int row = wrow + i * 16 + fm;
            int q = quad ^ ((row >> 1) & 3);
            a[i] = *(const bf16x8*)&As[row * 32 + q * 8];
        }
        #pragma unroll
        for (int j = 0; j < 2; ++j) {
            size_t off = (size_t)(j * 16 + fm) * 256 + kk * 32 + quad * 8;
            bh[j] = *(const bf16x8*)(bh_g + off);
            bl[j] = *(const bf16x8*)(bl_g + off);
        }
        #pragma unroll
        for (int i = 0; i < 2; ++i)
            #pragma unroll
            for (int j = 0; j < 2; ++j) {
                acc[i][j] = __builtin_amdgcn_mfma_f32_16x16x32_bf16(a[i], bh[j], acc[i][j], 0, 0, 0);
                acc[i][j] = __builtin_amdgcn_mfma_f32_16x16x32_bf16(a[i], bl[j], acc[i][j], 0, 0, 0);
            }
        __syncthreads();
    }

    // epilogue: write h2b (bf16) + fused attention scores (reduce over 32 cols)
    float a0 = as2[fm], a1 = as2[16 + fm];
    float d0 = ad2[fm], d1 = ad2[16 + fm];
    #pragma unroll
    for (int i = 0; i < 2; ++i) {
        #pragma unroll
        for (int r = 0; r < 4; ++r) {
            int rg = bm + wrow + i * 16 + quad * 4 + r;
            float v0 = acc[i][0][r], v1 = acc[i][1][r];
            float s1 = v0 * a0 + v1 * a1;
            float s2 = v0 * d0 + v1 * d1;
            #pragma unroll
            for (int off = 1; off < 16; off <<= 1) {
                s1 += __shfl_xor(s1, off);
                s2 += __shfl_xor(s2, off);
            }
            if (rg < M) {
                C[(size_t)rg * 32 + fm]      = (ushort)bf16_rne_bits(v0);
                C[(size_t)rg * 32 + 16 + fm] = (ushort)bf16_rne_bits(v1);
                if (fm == 0) { ssrc[rg] = s1; sdst[rg] = s2; }
            }
        }
    }
}

// ---------------------------------------------------------------- CSR build
__global__ void count_deg(const int* __restrict__ ei, int* __restrict__ deg) {
    int e = blockIdx.x * blockDim.x + threadIdx.x;
    if (e >= E2) return;
    int dst = (e < N_EDGES) ? ei[N_EDGES + e] : (e - N_EDGES);
    atomicAdd(&deg[dst], 1);
}

#define SCAN_B 256
#define SCAN_NB ((N_NODES + SCAN_B - 1) / SCAN_B)   // 196

__global__ void scan1_kernel(const int* __restrict__ deg, int* __restrict__ rowstart,
                             int* __restrict__ blocksum) {
    __shared__ int sm[SCAN_B];
    int t = threadIdx.x, i = blockIdx.x * SCAN_B + t;
    int v = (i < N_NODES) ? deg[i] : 0;
    sm[t] = v; __syncthreads();
    int x = v;
    for (int off = 1; off < SCAN_B; off <<= 1) {
        int y = (t >= off) ? sm[t - off] : 0; __syncthreads();
        x += y; sm[t] = x; __syncthreads();
    }
    if (i <= N_NODES) rowstart[i] = x - v;
    if (t == SCAN_B - 1) blocksum[blockIdx.x] = x;
}

__global__ void scan2_kernel(const int* __restrict__ blocksum, int* __restrict__ blockoff) {
    __shared__ int sm[256];
    int t = threadIdx.x;
    int v = (t < SCAN_NB) ? blocksum[t] : 0;
    sm[t] = v; __syncthreads();
    int x = v;
    for (int off = 1; off < 256; off <<= 1) {
        int y = (t >= off) ? sm[t - off] : 0; __syncthreads();
        x += y; sm[t] = x; __syncthreads();
    }
    if (t < SCAN_NB) blockoff[t] = x - v;
}

__global__ void fill_csr(const int* __restrict__ ei, const int* __restrict__ rowstart,
                         const int* __restrict__ blockoff,
                         int* __restrict__ cursor, int* __restrict__ csr_src) {
    int e = blockIdx.x * blockDim.x + threadIdx.x;
    if (e >= E2) return;
    int src, dst;
    if (e < N_EDGES) { src = ei[e]; dst = ei[N_EDGES + e]; }
    else             { src = e - N_EDGES; dst = src; }
    int p = atomicAdd(&cursor[dst], 1);
    csr_src[rowstart[dst] + blockoff[dst >> 8] + p] = src;
}

// ---------------------------------------------------------------- scores layer 1 (bf16 input)
__global__ void scores1_kernel(const ushort* __restrict__ h, const float* __restrict__ asrc,
                               const float* __restrict__ adst,
                               float* __restrict__ ssrc, float* __restrict__ sdst) {
    int gid = blockIdx.x * blockDim.x + threadIdx.x;
    int n = gid >> 3, hh = gid & 7;
    if (n >= N_NODES) return;
    const uint* hp = (const uint*)(h + (size_t)n * HC + hh * HID);  // 16 uints = 32 bf16
    const float* as = asrc + hh * HID;
    const float* ad = adst + hh * HID;
    float s1 = 0.f, s2 = 0.f;
    #pragma unroll
    for (int q = 0; q < 4; ++q) {
        uint4 u = ((const uint4*)hp)[q];
        uint w[4] = {u.x, u.y, u.z, u.w};
        #pragma unroll
        for (int k = 0; k < 4; ++k) {
            int c = q * 8 + k * 2;
            float v0 = __uint_as_float(w[k] << 16);
            float v1 = __uint_as_float(w[k] & 0xffff0000u);
            s1 += v0 * as[c] + v1 * as[c + 1];
            s2 += v0 * ad[c] + v1 * ad[c + 1];
        }
    }
    ssrc[n * HEADS + hh] = s1;
    sdst[n * HEADS + hh] = s2;
}

// ---------------------------------------------------------------- layer-1 aggregation
// one wave per node. lane -> head hg=lane>>3, channel quad lane*4.
// phase 2: 8-edge chunks; lane hl computes weight once, shfl-broadcast within head group.
__global__ void __launch_bounds__(256) agg1_wave_kernel(const ushort* __restrict__ h,
        const float* __restrict__ ssrc, const float* __restrict__ sdst,
        const int* __restrict__ rowstart, const int* __restrict__ blockoff,
        const int* __restrict__ csr_src,
        const float* __restrict__ bias, ushort* __restrict__ out) {
    const int wid = (blockIdx.x * blockDim.x + threadIdx.x) >> 6;   // node id
    if (wid >= N_NODES) return;
    const int lane = threadIdx.x & 63;
    const int hg = lane >> 3;
    const int hl = lane & 7;
    const int n = wid;
    const int beg = rowstart[n] + blockoff[n >> 8];
    const int end = rowstart[n + 1] + blockoff[(n + 1) >> 8];
    const float sdst_n = sdst[(size_t)n * HEADS + hg];

    // phase 1: per-head online softmax, 8 lanes per head
    float m = -INFINITY, s = 0.f;
    for (int e = beg + hl; e < end; e += 8) {
        int src = csr_src[e];
        float sc = ssrc[(size_t)src * HEADS + hg] + sdst_n;
        sc = sc > 0.f ? sc : NEG_SLOPE * sc;
        float nm = fmaxf(m, sc);
        s = s * __expf(m - nm) + __expf(sc - nm);
        m = nm;
    }
    #pragma unroll
    for (int off = 4; off > 0; off >>= 1) {
        float om = __shfl_xor(m, off);
        float os = __shfl_xor(s, off);
        float nm = fmaxf(m, om);
        float a = (m  == -INFINITY) ? 0.f : s  * __expf(m  - nm);
        float b = (om == -INFINITY) ? 0.f : os * __expf(om - nm);
        m = nm; s = a + b;
    }
    const float inv = 1.f / (s + 1e-16f);

    // phase 2: weight computed once per edge (by lane hl), broadcast to the head group
    float4 acc = make_float4(0.f, 0.f, 0.f, 0.f);
    const ushort* hc = h + lane * 4;
    const int base = hg << 3;
    for (int e = beg; e < end; e += 8) {
        int ee = e + hl;
        int src_h = 0; float w_h = 0.f;
        if (ee < end) {
            src_h = csr_src[ee];
            float sc = ssrc[(size_t)src_h * HEADS + hg] + sdst_n;
            sc = sc > 0.f ? sc : NEG_SLOPE * sc;
            w_h = __expf(sc - m) * inv;
        }
        #pragma unroll
        for (int j = 0; j < 8; ++j) {
            if (e + j >= end) break;              // wave-uniform
            float wj = __shfl(w_h, base + j);
            int   sj = __shfl(src_h, base + j);
            ushort4 v = *(const ushort4*)(hc + (size_t)sj * HC);
            acc.x += wj * bf2f(v.x);
            acc.y += wj * bf2f(v.y);
            acc.z += wj * bf2f(v.z);
            acc.w += wj * bf2f(v.w);
        }
    }
    float4 bv = *(const float4*)(bias + lane * 4);
    float4 o;
    o.x = acc.x + bv.x; o.y = acc.y + bv.y;
    o.z = acc.z + bv.z; o.w = acc.w + bv.w;
    o.x = o.x > 0.f ? o.x : expm1f(o.x);
    o.y = o.y > 0.f ? o.y : expm1f(o.y);
    o.z = o.z > 0.f ? o.z : expm1f(o.z);
    o.w = o.w > 0.f ? o.w : expm1f(o.w);
    ushort4 ob;
    ob.x = (ushort)bf16_rne_bits(o.x);
    ob.y = (ushort)bf16_rne_bits(o.y);
    ob.z = (ushort)bf16_rne_bits(o.z);
    ob.w = (ushort)bf16_rne_bits(o.w);
    *(ushort4*)(out + (size_t)n * HC + lane * 4) = ob;
}

// ---------------------------------------------------------------- layer-2 aggregation (bf16 gather)
__global__ void __launch_bounds__(64) agg2_kernel(const ushort* __restrict__ h2,
        const float* __restrict__ ssrc, const float* __restrict__ sdst,
        const int* __restrict__ rowstart, const int* __restrict__ blockoff,
        const int* __restrict__ csr_src,
        const float* __restrict__ bias, float* __restrict__ out) {
    const int n = blockIdx.x;
    const int beg = rowstart[n] + blockoff[n >> 8];
    const int end = rowstart[n + 1] + blockoff[(n + 1) >> 8];
    const int t = threadIdx.x;
    const float sdst_n = sdst[n];

    float m = -INFINITY, s = 0.f;
    for (int e = beg + t; e < end; e += 64) {
        float sc = ssrc[csr_src[e]] + sdst_n;
        sc = sc > 0.f ? sc : NEG_SLOPE * sc;
        float nm = fmaxf(m, sc);
        s = s * __expf(m - nm) + __expf(sc - nm);
        m = nm;
    }
    #pragma unroll
    for (int off = 32; off > 0; off >>= 1) {
        float om = __shfl_xor(m, off);
        float os = __shfl_xor(s, off);
        float nm = fmaxf(m, om);
        float a = (m  == -INFINITY) ? 0.f : s  * __expf(m  - nm);
        float b = (om == -INFINITY) ? 0.f : os * __expf(om - nm);
        m = nm; s = a + b;
    }
    const int slot = t >> 4, cp = t & 15;   // channels 2cp, 2cp+1
    float a0 = 0.f, a1 = 0.f;
    for (int e = beg + slot; e < end; e += 4) {
        int src = csr_src[e];
        float sc = ssrc[src] + sdst_n;
        sc = sc > 0.f ? sc : NEG_SLOPE * sc;
        float w = __expf(sc - m);
        uint v = *(const uint*)(h2 + (size_t)src * NCLASS + cp * 2);
        a0 += w * __uint_as_float(v << 16);
        a1 += w * __uint_as_float(v & 0xffff0000u);
    }
    a0 += __shfl_down(a0, 32); a1 += __shfl_down(a1, 32);
    a0 += __shfl_down(a0, 16); a1 += __shfl_down(a1, 16);
    if (t < 16) {
        float inv = 1.f / (s + 1e-16f);
        float2 o;
        o.x = a0 * inv + bias[cp * 2]     + 1e-6f;
        o.y = a1 * inv + bias[cp * 2 + 1] + 1e-6f;
        *(float2*)(out + (size_t)n * NCLASS + cp * 2) = o;
    }
}

// ---------------------------------------------------------------- launcher
extern "C" void kernel_launch(void* const* d_in, const int* in_sizes, int n_in,
                              void* d_out, int out_size, void* d_ws, size_t ws_size,
                              hipStream_t stream) {
    const float* x        = (const float*)d_in[0];
    const int*   ei       = (const int*)  d_in[1];
    const float* W1       = (const float*)d_in[2];
    const float* att_src1 = (const float*)d_in[3];
    const float* att_dst1 = (const float*)d_in[4];
    const float* b1       = (const float*)d_in[5];
    const float* W2       = (const float*)d_in[6];
    const float* att_src2 = (const float*)d_in[7];
    const float* att_dst2 = (const float*)d_in[8];
    const float* b2       = (const float*)d_in[9];
    float* out = (float*)d_out;

    // workspace layout (bf16 tables first; 16B alignment maintained)
    ushort* w1t_hi = (ushort*)d_ws;                        // 131072
    ushort* w1t_lo = w1t_hi + 256 * 512;                   // 131072
    ushort* w2t_hi = w1t_lo + 256 * 512;                   // 8192
    ushort* w2t_lo = w2t_hi + 32 * 256;                    // 8192
    ushort* h1b    = w2t_lo + 32 * 256;                    // N*HC bf16
    ushort* h2b    = h1b + (size_t)N_NODES * HC;           // N*NCLASS bf16
    ushort* out1b  = h2b + (size_t)N_NODES * NCLASS;       // N*HC bf16
    float* ssrc1 = (float*)(out1b + (size_t)N_NODES * HC); // N*HEADS
    float* sdst1 = ssrc1 + (size_t)N_NODES * HEADS;        // N*HEADS
    float* ssrc2 = sdst1 + (size_t)N_NODES * HEADS;        // N
    float* sdst2 = ssrc2 + N_NODES;                        // N
    int* rowstart = (int*)(sdst2 + N_NODES);               // N+1
    int* deg      = rowstart + N_NODES + 1;                // N   (deg+cursor zeroed together)
    int* cursor   = deg + N_NODES;                         // N
    int* csr_src  = cursor + N_NODES;                      // E2
    int* blocksum = csr_src + E2;                          // SCAN_NB
    int* blockoff = blocksum + SCAN_NB;                    // SCAN_NB

    // CSR build (rowstart kept block-local; consumers add blockoff[i>>8])
    hipMemsetAsync(deg, 0, 2 * N_NODES * sizeof(int), stream);   // deg + cursor
    int eb = (E2 + 255) / 256;
    count_deg<<<eb, 256, 0, stream>>>(ei, deg);
    scan1_kernel<<<SCAN_NB, SCAN_B, 0, stream>>>(deg, rowstart, blocksum);
    scan2_kernel<<<1, 256, 0, stream>>>(blocksum, blockoff);
    fill_csr<<<eb, 256, 0, stream>>>(ei, rowstart, blockoff, cursor, csr_src);

    // weight splits
    split_w1t_kernel<<<(256 * 512) / 256, 256, 0, stream>>>(W1, w1t_hi, w1t_lo);
    split_w2t_kernel<<<(32 * 256) / 256, 256, 0, stream>>>(W2, w2t_hi, w2t_lo);

    // layer 1: MFMA GEMM -> bf16 h1
    {
        dim3 grid((N_NODES + 127) / 128, HC / 128);
        gemm1_mfma_kernel<<<grid, 256, 0, stream>>>((const uint*)x, w1t_hi, w1t_lo, h1b, N_NODES);
    }
    scores1_kernel<<<(N_NODES * HEADS + 255) / 256, 256, 0, stream>>>(h1b, att_src1, att_dst1, ssrc1, sdst1);
    agg1_wave_kernel<<<(N_NODES + 3) / 4, 256, 0, stream>>>(h1b, ssrc1, sdst1, rowstart, blockoff, csr_src, b1, out1b);

    // layer 2: MFMA GEMM -> bf16 h2 + fused scores2
    gemm2_mfma_kernel<<<(N_NODES + 127) / 128, 256, 0, stream>>>(out1b, w2t_hi, w2t_lo,
            att_src2, att_dst2, h2b, ssrc2, sdst2, N_NODES);
    agg2_kernel<<<N_NODES, 64, 0, stream>>>(h2b, ssrc2, sdst2, rowstart, blockoff, csr_src, b2, out);
}

// Round 7
// 404.158 us; speedup vs baseline: 1.9460x; 1.0998x over previous
//
#include <hip/hip_runtime.h>
#include <math.h>

#define N_NODES 50000
#define N_EDGES 800000
#define E2 (N_EDGES + N_NODES)   // with self loops
#define F_IN 512
#define HEADS 8
#define HID 32
#define HC 256                    // HEADS*HID
#define NCLASS 32
#define NEG_SLOPE 0.2f

typedef unsigned int uint;
typedef unsigned short ushort;
typedef __attribute__((ext_vector_type(8))) short bf16x8;   // 8 bf16 (4 VGPRs)
typedef __attribute__((ext_vector_type(4))) float f32x4;

#define GLOBAL_LOAD_LDS16(g, l) \
    __builtin_amdgcn_global_load_lds((const __attribute__((address_space(1))) void*)(g), \
                                     (__attribute__((address_space(3))) void*)(l), 16, 0, 0)

__device__ inline uint bf16_rne_bits(float f) {
    uint u = __float_as_uint(f);
    return (u + 0x7fffu + ((u >> 16) & 1u)) >> 16;
}
__device__ inline float bf2f(ushort u) { return __uint_as_float(((uint)u) << 16); }

// ------------------------------------------------ W1 [512][256] -> W1^T hi/lo bf16 [256][512]
__global__ void split_w1t_kernel(const float* __restrict__ W1,
                                 ushort* __restrict__ hi, ushort* __restrict__ lo) {
    int t = blockIdx.x * 256 + threadIdx.x;      // t = n*512 + k, t < 131072
    int n = t >> 9, k = t & 511;
    float f = W1[k * 256 + n];
    uint h = bf16_rne_bits(f);
    float r = f - __uint_as_float(h << 16);
    hi[t] = (ushort)h;
    lo[t] = (ushort)bf16_rne_bits(r);
}

// ------------------------------------------------ W2 [256][32] -> W2^T hi/lo bf16 [32][256]
__global__ void split_w2t_kernel(const float* __restrict__ W2,
                                 ushort* __restrict__ hi, ushort* __restrict__ lo) {
    int t = blockIdx.x * 256 + threadIdx.x;      // t = n*256 + k, t < 8192
    int n = t >> 8, k = t & 255;
    float f = W2[k * 32 + n];
    uint h = bf16_rne_bits(f);
    float r = f - __uint_as_float(h << 16);
    hi[t] = (ushort)h;
    lo[t] = (ushort)bf16_rne_bits(r);
}

// ------------------------------------------------ MFMA GEMM1: h1b[M,256] = x @ W1 (split bf16, 3-term)
// + fused scores1 (from fp32 acc, reduced across fm lanes)
__global__ void __launch_bounds__(256) gemm1_mfma_kernel(const uint* __restrict__ xp,
        const ushort* __restrict__ bhi, const ushort* __restrict__ blo,
        const float* __restrict__ as1, const float* __restrict__ ad1,
        ushort* __restrict__ C, float* __restrict__ ssrc, float* __restrict__ sdst, int M) {
    __shared__ uint   As[128 * 32];   // 16 KB fp32 bits, chunk-swizzled: phys chunk = row*8 + (c ^ (row&7))
    __shared__ ushort Bh[128 * 32];   // 8 KB,  phys chunk = row*4 + (q ^ ((row>>1)&3))
    __shared__ ushort Bl[128 * 32];   // 8 KB
    const int tid = threadIdx.x, lane = tid & 63, wave = tid >> 6;
    const int bm = blockIdx.x * 128, bn = blockIdx.y * 128;

    const uint* agp[4]; const uint* alp[4];
    #pragma unroll
    for (int s = 0; s < 4; ++s) {
        int t = wave * 4 + s;
        int p = t * 64 + lane;           // physical chunk 0..1023
        int row = p >> 3, cs = p & 7;
        int c = cs ^ (row & 7);          // global k-chunk (4 u32 each)
        int grow = bm + row; if (grow > M - 1) grow = M - 1;
        agp[s] = xp + ((size_t)grow * 512 + c * 4);
        alp[s] = &As[t * 256];           // wave-uniform LDS base; HW adds lane*16B
    }
    const ushort* bhgp[2]; const ushort* blgp[2]; const ushort* bhlp[2]; const ushort* bllp[2];
    #pragma unroll
    for (int s = 0; s < 2; ++s) {
        int t = wave * 2 + s;
        int p = t * 64 + lane;           // physical chunk 0..511
        int row = p >> 2, qs = p & 3;
        int q = qs ^ ((row >> 1) & 3);   // global k-chunk (8 bf16 each)
        size_t go = (size_t)(bn + row) * 512 + q * 8;
        bhgp[s] = bhi + go; blgp[s] = blo + go;
        bhlp[s] = &Bh[t * 512]; bllp[s] = &Bl[t * 512];
    }

    f32x4 acc[4][4] = {};
    const int wm = (wave >> 1) * 64, wn = (wave & 1) * 64;
    const int fm = lane & 15, quad = lane >> 4;

    for (int kk = 0; kk < 16; ++kk) {
        #pragma unroll
        for (int s = 0; s < 4; ++s) GLOBAL_LOAD_LDS16(agp[s], alp[s]);
        #pragma unroll
        for (int s = 0; s < 2; ++s) {
            GLOBAL_LOAD_LDS16(bhgp[s], bhlp[s]);
            GLOBAL_LOAD_LDS16(blgp[s], bllp[s]);
        }
        #pragma unroll
        for (int s = 0; s < 4; ++s) agp[s] += 32;
        #pragma unroll
        for (int s = 0; s < 2; ++s) { bhgp[s] += 32; blgp[s] += 32; }
        __syncthreads();

        bf16x8 ah[4], al[4], bh[4], bl[4];
        #pragma unroll
        for (int i = 0; i < 4; ++i) {
            int row = wm + i * 16 + fm;
            int sw = row & 7;
            uint4 c0 = *(const uint4*)&As[row * 32 + (((2 * quad)     ^ sw) * 4)];
            uint4 c1 = *(const uint4*)&As[row * 32 + (((2 * quad + 1) ^ sw) * 4)];
            union { uint u[4]; bf16x8 v; } H, L;
            H.u[0] = __builtin_amdgcn_perm(c0.y, c0.x, 0x07060302u);
            H.u[1] = __builtin_amdgcn_perm(c0.w, c0.z, 0x07060302u);
            H.u[2] = __builtin_amdgcn_perm(c1.y, c1.x, 0x07060302u);
            H.u[3] = __builtin_amdgcn_perm(c1.w, c1.z, 0x07060302u);
            uint r0 = __float_as_uint(__uint_as_float(c0.x) - __uint_as_float(c0.x & 0xffff0000u));
            uint r1 = __float_as_uint(__uint_as_float(c0.y) - __uint_as_float(c0.y & 0xffff0000u));
            uint r2 = __float_as_uint(__uint_as_float(c0.z) - __uint_as_float(c0.z & 0xffff0000u));
            uint r3 = __float_as_uint(__uint_as_float(c0.w) - __uint_as_float(c0.w & 0xffff0000u));
            uint r4 = __float_as_uint(__uint_as_float(c1.x) - __uint_as_float(c1.x & 0xffff0000u));
            uint r5 = __float_as_uint(__uint_as_float(c1.y) - __uint_as_float(c1.y & 0xffff0000u));
            uint r6 = __float_as_uint(__uint_as_float(c1.z) - __uint_as_float(c1.z & 0xffff0000u));
            uint r7 = __float_as_uint(__uint_as_float(c1.w) - __uint_as_float(c1.w & 0xffff0000u));
            L.u[0] = __builtin_amdgcn_perm(r1, r0, 0x07060302u);
            L.u[1] = __builtin_amdgcn_perm(r3, r2, 0x07060302u);
            L.u[2] = __builtin_amdgcn_perm(r5, r4, 0x07060302u);
            L.u[3] = __builtin_amdgcn_perm(r7, r6, 0x07060302u);
            ah[i] = H.v; al[i] = L.v;
        }
        #pragma unroll
        for (int j = 0; j < 4; ++j) {
            int row = wn + j * 16 + fm;
            int qs = quad ^ ((row >> 1) & 3);
            bh[j] = *(const bf16x8*)&Bh[row * 32 + qs * 8];
            bl[j] = *(const bf16x8*)&Bl[row * 32 + qs * 8];
        }
        #pragma unroll
        for (int i = 0; i < 4; ++i)
            #pragma unroll
            for (int j = 0; j < 4; ++j) {
                acc[i][j] = __builtin_amdgcn_mfma_f32_16x16x32_bf16(ah[i], bh[j], acc[i][j], 0, 0, 0);
                acc[i][j] = __builtin_amdgcn_mfma_f32_16x16x32_bf16(ah[i], bl[j], acc[i][j], 0, 0, 0);
                acc[i][j] = __builtin_amdgcn_mfma_f32_16x16x32_bf16(al[i], bh[j], acc[i][j], 0, 0, 0);
            }
        __syncthreads();
    }

    // epilogue 1: h1b bf16 write (C/D layout col=lane&15, row=quad*4+reg)
    #pragma unroll
    for (int i = 0; i < 4; ++i) {
        int rb = bm + wm + i * 16 + quad * 4;
        #pragma unroll
        for (int j = 0; j < 4; ++j) {
            int col = bn + wn + j * 16 + fm;
            #pragma unroll
            for (int r = 0; r < 4; ++r) {
                int row = rb + r;
                if (row < M) C[(size_t)row * 256 + col] = (ushort)bf16_rne_bits(acc[i][j][r]);
            }
        }
    }

    // epilogue 2: fused scores1. This wave's cols = heads head0, head0+1.
    const int head0 = (bn + wn) >> 5;
    const float asA0 = as1[head0 * 32 + fm],      asA1 = as1[head0 * 32 + 16 + fm];
    const float asB0 = as1[head0 * 32 + 32 + fm], asB1 = as1[head0 * 32 + 48 + fm];
    const float adA0 = ad1[head0 * 32 + fm],      adA1 = ad1[head0 * 32 + 16 + fm];
    const float adB0 = ad1[head0 * 32 + 32 + fm], adB1 = ad1[head0 * 32 + 48 + fm];
    #pragma unroll
    for (int i = 0; i < 4; ++i) {
        #pragma unroll
        for (int r = 0; r < 4; ++r) {
            int row = bm + wm + i * 16 + quad * 4 + r;
            float s1A = acc[i][0][r] * asA0 + acc[i][1][r] * asA1;
            float s1B = acc[i][2][r] * asB0 + acc[i][3][r] * asB1;
            float s2A = acc[i][0][r] * adA0 + acc[i][1][r] * adA1;
            float s2B = acc[i][2][r] * adB0 + acc[i][3][r] * adB1;
            #pragma unroll
            for (int off = 1; off < 16; off <<= 1) {   // reduce across fm (stays in quad group)
                s1A += __shfl_xor(s1A, off);
                s1B += __shfl_xor(s1B, off);
                s2A += __shfl_xor(s2A, off);
                s2B += __shfl_xor(s2B, off);
            }
            if (fm == 0 && row < M) {
                ssrc[(size_t)row * 8 + head0]     = s1A;
                ssrc[(size_t)row * 8 + head0 + 1] = s1B;
                sdst[(size_t)row * 8 + head0]     = s2A;
                sdst[(size_t)row * 8 + head0 + 1] = s2B;
            }
        }
    }
}

// ------------------------------------------------ MFMA GEMM2: h2b[M,32] = out1b @ W2 (2-term) + fused scores2
__global__ void __launch_bounds__(256) gemm2_mfma_kernel(const ushort* __restrict__ A,
        const ushort* __restrict__ bh_g, const ushort* __restrict__ bl_g,
        const float* __restrict__ as2, const float* __restrict__ ad2,
        ushort* __restrict__ C, float* __restrict__ ssrc, float* __restrict__ sdst, int M) {
    __shared__ ushort As[128 * 32];   // 8 KB, phys chunk = row*4 + (q ^ ((row>>1)&3))
    const int tid = threadIdx.x, lane = tid & 63, wave = tid >> 6;
    const int bm = blockIdx.x * 128;
    const int fm = lane & 15, quad = lane >> 4;
    const int wrow = wave * 32;

    const ushort* agp[2]; const ushort* alp[2];
    #pragma unroll
    for (int s = 0; s < 2; ++s) {
        int t = wave * 2 + s;
        int p = t * 64 + lane;           // chunk 0..511
        int row = p >> 2, qs = p & 3;
        int q = qs ^ ((row >> 1) & 3);
        int gr = bm + row; if (gr > M - 1) gr = M - 1;
        agp[s] = A + (size_t)gr * 256 + q * 8;
        alp[s] = &As[t * 512];
    }

    f32x4 acc[2][2] = {};
    for (int kk = 0; kk < 8; ++kk) {
        GLOBAL_LOAD_LDS16(agp[0], alp[0]);
        GLOBAL_LOAD_LDS16(agp[1], alp[1]);
        agp[0] += 32; agp[1] += 32;
        __syncthreads();
        bf16x8 a[2], bh[2], bl[2];
        #pragma unroll
        for (int i = 0; i < 2; ++i) {
            int row = wrow + i * 16 + fm;
            int q = quad ^ ((row >> 1) & 3);
            a[i] = *(const bf16x8*)&As[row * 32 + q * 8];
        }
        #pragma unroll
        for (int j = 0; j < 2; ++j) {
            size_t off = (size_t)(j * 16 + fm) * 256 + kk * 32 + quad * 8;
            bh[j] = *(const bf16x8*)(bh_g + off);
            bl[j] = *(const bf16x8*)(bl_g + off);
        }
        #pragma unroll
        for (int i = 0; i < 2; ++i)
            #pragma unroll
            for (int j = 0; j < 2; ++j) {
                acc[i][j] = __builtin_amdgcn_mfma_f32_16x16x32_bf16(a[i], bh[j], acc[i][j], 0, 0, 0);
                acc[i][j] = __builtin_amdgcn_mfma_f32_16x16x32_bf16(a[i], bl[j], acc[i][j], 0, 0, 0);
            }
        __syncthreads();
    }

    float a0 = as2[fm], a1 = as2[16 + fm];
    float d0 = ad2[fm], d1 = ad2[16 + fm];
    #pragma unroll
    for (int i = 0; i < 2; ++i) {
        #pragma unroll
        for (int r = 0; r < 4; ++r) {
            int rg = bm + wrow + i * 16 + quad * 4 + r;
            float v0 = acc[i][0][r], v1 = acc[i][1][r];
            float s1 = v0 * a0 + v1 * a1;
            float s2 = v0 * d0 + v1 * d1;
            #pragma unroll
            for (int off = 1; off < 16; off <<= 1) {
                s1 += __shfl_xor(s1, off);
                s2 += __shfl_xor(s2, off);
            }
            if (rg < M) {
                C[(size_t)rg * 32 + fm]      = (ushort)bf16_rne_bits(v0);
                C[(size_t)rg * 32 + 16 + fm] = (ushort)bf16_rne_bits(v1);
                if (fm == 0) { ssrc[rg] = s1; sdst[rg] = s2; }
            }
        }
    }
}

// ---------------------------------------------------------------- CSR build
__global__ void count_deg(const int* __restrict__ ei, int* __restrict__ deg) {
    int e = blockIdx.x * blockDim.x + threadIdx.x;
    if (e >= E2) return;
    int dst = (e < N_EDGES) ? ei[N_EDGES + e] : (e - N_EDGES);
    atomicAdd(&deg[dst], 1);
}

#define SCAN_B 256
#define SCAN_NB ((N_NODES + SCAN_B - 1) / SCAN_B)   // 196

__global__ void scan1_kernel(const int* __restrict__ deg, int* __restrict__ rowstart,
                             int* __restrict__ blocksum) {
    __shared__ int sm[SCAN_B];
    int t = threadIdx.x, i = blockIdx.x * SCAN_B + t;
    int v = (i < N_NODES) ? deg[i] : 0;
    sm[t] = v; __syncthreads();
    int x = v;
    for (int off = 1; off < SCAN_B; off <<= 1) {
        int y = (t >= off) ? sm[t - off] : 0; __syncthreads();
        x += y; sm[t] = x; __syncthreads();
    }
    if (i <= N_NODES) rowstart[i] = x - v;
    if (t == SCAN_B - 1) blocksum[blockIdx.x] = x;
}

__global__ void scan2_kernel(const int* __restrict__ blocksum, int* __restrict__ blockoff) {
    __shared__ int sm[256];
    int t = threadIdx.x;
    int v = (t < SCAN_NB) ? blocksum[t] : 0;
    sm[t] = v; __syncthreads();
    int x = v;
    for (int off = 1; off < 256; off <<= 1) {
        int y = (t >= off) ? sm[t - off] : 0; __syncthreads();
        x += y; sm[t] = x; __syncthreads();
    }
    if (t < SCAN_NB) blockoff[t] = x - v;
}

__global__ void fill_csr(const int* __restrict__ ei, const int* __restrict__ rowstart,
                         const int* __restrict__ blockoff,
                         int* __restrict__ cursor, int* __restrict__ csr_src) {
    int e = blockIdx.x * blockDim.x + threadIdx.x;
    if (e >= E2) return;
    int src, dst;
    if (e < N_EDGES) { src = ei[e]; dst = ei[N_EDGES + e]; }
    else             { src = e - N_EDGES; dst = src; }
    int p = atomicAdd(&cursor[dst], 1);
    csr_src[rowstart[dst] + blockoff[dst >> 8] + p] = src;
}

// ---------------------------------------------------------------- layer-1 aggregation
// one wave per node; SINGLE PASS (no-max softmax): acc = sum w*h, sw = sum w.
// weight computed once per edge per head (lane hl of head group hg), batched
// shuffle-broadcast then 8 loads in flight.
__global__ void __launch_bounds__(256) agg1_wave_kernel(const ushort* __restrict__ h,
        const float* __restrict__ ssrc, const float* __restrict__ sdst,
        const int* __restrict__ rowstart, const int* __restrict__ blockoff,
        const int* __restrict__ csr_src,
        const float* __restrict__ bias, ushort* __restrict__ out) {
    const int wid = (blockIdx.x * blockDim.x + threadIdx.x) >> 6;   // node id
    if (wid >= N_NODES) return;
    const int lane = threadIdx.x & 63;
    const int hg = lane >> 3;
    const int hl = lane & 7;
    const int n = wid;
    const int beg = rowstart[n] + blockoff[n >> 8];
    const int end = rowstart[n + 1] + blockoff[(n + 1) >> 8];
    const float sdst_n = sdst[(size_t)n * HEADS + hg];

    float4 acc = make_float4(0.f, 0.f, 0.f, 0.f);
    float sw = 0.f;
    const ushort* hc = h + lane * 4;
    const int base = hg << 3;
    for (int e = beg; e < end; e += 8) {
        int ee = e + hl;
        int eidx = ee < end ? ee : end - 1;
        int src_h = csr_src[eidx];
        float sc = ssrc[(size_t)src_h * HEADS + hg] + sdst_n;
        sc = sc > 0.f ? sc : NEG_SLOPE * sc;
        float w_h = (ee < end) ? __expf(sc) : 0.f;
        float wj[8]; int sj[8];
        #pragma unroll
        for (int j = 0; j < 8; ++j) {
            wj[j] = __shfl(w_h, base + j);
            sj[j] = __shfl(src_h, base + j);
        }
        ushort4 v[8];
        #pragma unroll
        for (int j = 0; j < 8; ++j) v[j] = *(const ushort4*)(hc + (size_t)sj[j] * HC);
        #pragma unroll
        for (int j = 0; j < 8; ++j) {
            acc.x += wj[j] * bf2f(v[j].x);
            acc.y += wj[j] * bf2f(v[j].y);
            acc.z += wj[j] * bf2f(v[j].z);
            acc.w += wj[j] * bf2f(v[j].w);
            sw += wj[j];
        }
    }
    float inv = 1.f / (sw + 1e-16f);
    float4 bv = *(const float4*)(bias + lane * 4);
    float4 o;
    o.x = acc.x * inv + bv.x; o.y = acc.y * inv + bv.y;
    o.z = acc.z * inv + bv.z; o.w = acc.w * inv + bv.w;
    o.x = o.x > 0.f ? o.x : expm1f(o.x);
    o.y = o.y > 0.f ? o.y : expm1f(o.y);
    o.z = o.z > 0.f ? o.z : expm1f(o.z);
    o.w = o.w > 0.f ? o.w : expm1f(o.w);
    ushort4 ob;
    ob.x = (ushort)bf16_rne_bits(o.x);
    ob.y = (ushort)bf16_rne_bits(o.y);
    ob.z = (ushort)bf16_rne_bits(o.z);
    ob.w = (ushort)bf16_rne_bits(o.w);
    *(ushort4*)(out + (size_t)n * HC + lane * 4) = ob;
}

// ---------------------------------------------------------------- layer-2 aggregation (single pass)
__global__ void __launch_bounds__(64) agg2_kernel(const ushort* __restrict__ h2,
        const float* __restrict__ ssrc, const float* __restrict__ sdst,
        const int* __restrict__ rowstart, const int* __restrict__ blockoff,
        const int* __restrict__ csr_src,
        const float* __restrict__ bias, float* __restrict__ out) {
    const int n = blockIdx.x;
    const int beg = rowstart[n] + blockoff[n >> 8];
    const int end = rowstart[n + 1] + blockoff[(n + 1) >> 8];
    const int t = threadIdx.x;
    const float sdst_n = sdst[n];

    const int slot = t >> 4, cp = t & 15;   // channels 2cp, 2cp+1
    float a0 = 0.f, a1 = 0.f, sw = 0.f;
    for (int e = beg + slot; e < end; e += 4) {
        int src = csr_src[e];
        float sc = ssrc[src] + sdst_n;
        sc = sc > 0.f ? sc : NEG_SLOPE * sc;
        float w = __expf(sc);
        uint v = *(const uint*)(h2 + (size_t)src * NCLASS + cp * 2);
        a0 += w * __uint_as_float(v << 16);
        a1 += w * __uint_as_float(v & 0xffff0000u);
        sw += w;
    }
    a0 += __shfl_down(a0, 32); a1 += __shfl_down(a1, 32); sw += __shfl_down(sw, 32);
    a0 += __shfl_down(a0, 16); a1 += __shfl_down(a1, 16); sw += __shfl_down(sw, 16);
    if (t < 16) {
        float inv = 1.f / (sw + 1e-16f);
        float2 o;
        o.x = a0 * inv + bias[cp * 2]     + 1e-6f;
        o.y = a1 * inv + bias[cp * 2 + 1] + 1e-6f;
        *(float2*)(out + (size_t)n * NCLASS + cp * 2) = o;
    }
}

// ---------------------------------------------------------------- launcher
extern "C" void kernel_launch(void* const* d_in, const int* in_sizes, int n_in,
                              void* d_out, int out_size, void* d_ws, size_t ws_size,
                              hipStream_t stream) {
    const float* x        = (const float*)d_in[0];
    const int*   ei       = (const int*)  d_in[1];
    const float* W1       = (const float*)d_in[2];
    const float* att_src1 = (const float*)d_in[3];
    const float* att_dst1 = (const float*)d_in[4];
    const float* b1       = (const float*)d_in[5];
    const float* W2       = (const float*)d_in[6];
    const float* att_src2 = (const float*)d_in[7];
    const float* att_dst2 = (const float*)d_in[8];
    const float* b2       = (const float*)d_in[9];
    float* out = (float*)d_out;

    // workspace layout
    ushort* w1t_hi = (ushort*)d_ws;                        // 131072
    ushort* w1t_lo = w1t_hi + 256 * 512;                   // 131072
    ushort* w2t_hi = w1t_lo + 256 * 512;                   // 8192
    ushort* w2t_lo = w2t_hi + 32 * 256;                    // 8192
    ushort* h1b    = w2t_lo + 32 * 256;                    // N*HC bf16
    ushort* h2b    = h1b + (size_t)N_NODES * HC;           // N*NCLASS bf16
    ushort* out1b  = h2b + (size_t)N_NODES * NCLASS;       // N*HC bf16
    float* ssrc1 = (float*)(out1b + (size_t)N_NODES * HC); // N*HEADS
    float* sdst1 = ssrc1 + (size_t)N_NODES * HEADS;        // N*HEADS
    float* ssrc2 = sdst1 + (size_t)N_NODES * HEADS;        // N
    float* sdst2 = ssrc2 + N_NODES;                        // N
    int* rowstart = (int*)(sdst2 + N_NODES);               // N+1
    int* deg      = rowstart + N_NODES + 1;                // N   (deg+cursor zeroed together)
    int* cursor   = deg + N_NODES;                         // N
    int* csr_src  = cursor + N_NODES;                      // E2
    int* blocksum = csr_src + E2;                          // SCAN_NB
    int* blockoff = blocksum + SCAN_NB;                    // SCAN_NB

    // CSR build (rowstart kept block-local; consumers add blockoff[i>>8])
    hipMemsetAsync(deg, 0, 2 * N_NODES * sizeof(int), stream);   // deg + cursor
    int eb = (E2 + 255) / 256;
    count_deg<<<eb, 256, 0, stream>>>(ei, deg);
    scan1_kernel<<<SCAN_NB, SCAN_B, 0, stream>>>(deg, rowstart, blocksum);
    scan2_kernel<<<1, 256, 0, stream>>>(blocksum, blockoff);
    fill_csr<<<eb, 256, 0, stream>>>(ei, rowstart, blockoff, cursor, csr_src);

    // weight splits
    split_w1t_kernel<<<(256 * 512) / 256, 256, 0, stream>>>(W1, w1t_hi, w1t_lo);
    split_w2t_kernel<<<(32 * 256) / 256, 256, 0, stream>>>(W2, w2t_hi, w2t_lo);

    // layer 1: MFMA GEMM -> bf16 h1 + fused scores1
    {
        dim3 grid((N_NODES + 127) / 128, HC / 128);
        gemm1_mfma_kernel<<<grid, 256, 0, stream>>>((const uint*)x, w1t_hi, w1t_lo,
                att_src1, att_dst1, h1b, ssrc1, sdst1, N_NODES);
    }
    agg1_wave_kernel<<<(N_NODES + 3) / 4, 256, 0, stream>>>(h1b, ssrc1, sdst1, rowstart, blockoff, csr_src, b1, out1b);

    // layer 2: MFMA GEMM -> bf16 h2 + fused scores2
    gemm2_mfma_kernel<<<(N_NODES + 127) / 128, 256, 0, stream>>>(out1b, w2t_hi, w2t_lo,
            att_src2, att_dst2, h2b, ssrc2, sdst2, N_NODES);
    agg2_kernel<<<N_NODES, 64, 0, stream>>>(h2b, ssrc2, sdst2, rowstart, blockoff, csr_src, b2, out);
}